// Round 4
// baseline (196.049 us; speedup 1.0000x reference)
//
#include <hip/hip_runtime.h>
#include <hip/hip_bf16.h>
#include <stdint.h>

typedef short bf16x8 __attribute__((ext_vector_type(8)));
typedef short bf16x4 __attribute__((ext_vector_type(4)));
typedef float f32x4  __attribute__((ext_vector_type(4)));

__device__ __forceinline__ unsigned short f2bf(float x) {
    unsigned int u = __float_as_uint(x);
    unsigned int r = (u + 0x7fffu + ((u >> 16) & 1u)) >> 16;
    return (unsigned short)r;
}
__device__ __forceinline__ float bf2f(unsigned short h) {
    return __uint_as_float(((unsigned int)h) << 16);
}
__device__ __forceinline__ float4 fma4(float4 z, float s, float4 a) {
    a.x = fmaf(z.x, s, a.x); a.y = fmaf(z.y, s, a.y);
    a.z = fmaf(z.z, s, a.z); a.w = fmaf(z.w, s, a.w);
    return a;
}

// q pre-scale: (1/sqrt(64)) * log2(e)  -> scores come out in log2 units
#define QSCALE 0.18033688f

// ---------------------------------------------------------------------------
// proj_q: q[b, i*64+j, d] = (zx@qw + qb + PE·pxw + pxb) * 0.125*log2e
// PE collapses: sin(4i)*A[d] + cos(4i)*B[d] + sin(4j)*C[d] + cos(4j)*E[d] + F[d]
// grid 128 = (b, i). Output: split bf16 (hi, lo), pre-scaled.
// ---------------------------------------------------------------------------
__global__ __launch_bounds__(256) void proj_q_kernel(
    const float* __restrict__ zx, const float* __restrict__ qw, const float* __restrict__ qb,
    const float* __restrict__ pxw, const float* __restrict__ pxb,
    unsigned short* __restrict__ qhi, unsigned short* __restrict__ qlo)
{
    const int b = blockIdx.x >> 6;
    const int i = blockIdx.x & 63;
    const int tid = threadIdx.x;
    __shared__ __align__(16) float zt[64][68];
    __shared__ __align__(16) float wt[64][68];
    __shared__ float Af[64], Bf[64], Cf[64], Ef[64], Ff[64], sw[64], cw[64];

    {
        const int w = tid & 63, c0 = tid >> 6;
        #pragma unroll
        for (int cc = 0; cc < 16; ++cc) {
            int c = cc * 4 + c0;
            zt[c][w] = zx[((b * 64 + c) * 64 + i) * 64 + w];
        }
        #pragma unroll
        for (int ii = 0; ii < 16; ++ii) {
            int idx = tid + 256 * ii;
            wt[idx >> 6][idx & 63] = qw[idx];
        }
    }
    if (tid < 64) {
        int d = tid;
        float A = 0.f;
        for (int c = 0; c < 16; ++c) A += pxw[c * 64 + d];
        float F = 0.f;
        for (int c = 19; c < 64; ++c) F += pxw[c * 64 + d];
        Af[d] = A; Bf[d] = pxw[16 * 64 + d]; Cf[d] = pxw[17 * 64 + d]; Ef[d] = pxw[18 * 64 + d];
        Ff[d] = F + pxb[d] + qb[d];
        sw[d] = sinf(4.0f * (float)d); cw[d] = cosf(4.0f * (float)d);
    }
    __syncthreads();

    const int d = tid & 63, wb = (tid >> 6) * 16;
    float4 a0 = {0,0,0,0}, a1 = {0,0,0,0}, a2 = {0,0,0,0}, a3 = {0,0,0,0};
    for (int c = 0; c < 64; ++c) {
        float wvv = wt[c][d];
        const float4* zp = (const float4*)&zt[c][wb];
        a0 = fma4(zp[0], wvv, a0); a1 = fma4(zp[1], wvv, a1);
        a2 = fma4(zp[2], wvv, a2); a3 = fma4(zp[3], wvv, a3);
    }
    float acc[16] = {a0.x,a0.y,a0.z,a0.w, a1.x,a1.y,a1.z,a1.w,
                     a2.x,a2.y,a2.z,a2.w, a3.x,a3.y,a3.z,a3.w};
    float pe0 = sw[i] * Af[d] + cw[i] * Bf[d] + Ff[d];
    #pragma unroll
    for (int jj = 0; jj < 16; ++jj) {
        int j = wb + jj;
        float val = (acc[jj] + pe0 + sw[j] * Cf[d] + cw[j] * Ef[d]) * QSCALE;
        int idx = (b * 4096 + i * 64 + j) * 64 + d;
        unsigned short hi = f2bf(val);
        qhi[idx] = hi;
        qlo[idx] = f2bf(val - bf2f(hi));
    }
}

// ---------------------------------------------------------------------------
// proj_kv: k = zy@kw + kb + PE·pyw + pyb  (split bf16, [B][16384][64])
//          v = zy@vw + vb                 (bf16, TRANSPOSED [B][64][16384])
// grid 512 = (b, kimg, h).
// ---------------------------------------------------------------------------
__global__ __launch_bounds__(256) void proj_kv_kernel(
    const float* __restrict__ zy,
    const float* __restrict__ kw, const float* __restrict__ kb_,
    const float* __restrict__ pyw, const float* __restrict__ pyb,
    const float* __restrict__ vw, const float* __restrict__ vb_,
    unsigned short* __restrict__ khi, unsigned short* __restrict__ klo,
    unsigned short* __restrict__ vt)
{
    const int bk = blockIdx.x >> 6;     // 0..7
    const int b = bk >> 2, kimg = bk & 3;
    const int h = blockIdx.x & 63;
    const int tid = threadIdx.x;
    __shared__ __align__(16) float zt[64][68];
    __shared__ __align__(16) float kwt[64][68];
    __shared__ __align__(16) float vwt[64][68];
    __shared__ float A2[64], B2[64], C2[64], E2[64], F2[64], vb[64], sw[64], cw[64];

    {
        const int w = tid & 63, c0 = tid >> 6;
        #pragma unroll
        for (int cc = 0; cc < 16; ++cc) {
            int c = cc * 4 + c0;
            zt[c][w] = zy[(((b * 4 + kimg) * 64 + c) * 64 + h) * 64 + w];
        }
        #pragma unroll
        for (int ii = 0; ii < 16; ++ii) {
            int idx = tid + 256 * ii;
            kwt[idx >> 6][idx & 63] = kw[idx];
            vwt[idx >> 6][idx & 63] = vw[idx];
        }
    }
    if (tid < 64) {
        int d = tid;
        float A = 0.f;
        for (int c = 0; c < 16; ++c) A += pyw[c * 64 + d];
        float F = 0.f;
        for (int c = 19; c < 64; ++c) F += pyw[c * 64 + d];
        A2[d] = A; B2[d] = pyw[16 * 64 + d]; C2[d] = pyw[17 * 64 + d]; E2[d] = pyw[18 * 64 + d];
        F2[d] = F + pyb[d] + kb_[d];
        vb[d] = vb_[d];
        sw[d] = sinf(4.0f * (float)d); cw[d] = cosf(4.0f * (float)d);
    }
    __syncthreads();

    const int d = tid & 63, wb = (tid >> 6) * 16;
    float4 ka0 = {0,0,0,0}, ka1 = {0,0,0,0}, ka2 = {0,0,0,0}, ka3 = {0,0,0,0};
    float4 va0 = {0,0,0,0}, va1 = {0,0,0,0}, va2 = {0,0,0,0}, va3 = {0,0,0,0};
    for (int c = 0; c < 64; ++c) {
        float wk = kwt[c][d], wvv = vwt[c][d];
        const float4* zp = (const float4*)&zt[c][wb];
        float4 z0 = zp[0], z1 = zp[1], z2 = zp[2], z3 = zp[3];
        ka0 = fma4(z0, wk, ka0); ka1 = fma4(z1, wk, ka1);
        ka2 = fma4(z2, wk, ka2); ka3 = fma4(z3, wk, ka3);
        va0 = fma4(z0, wvv, va0); va1 = fma4(z1, wvv, va1);
        va2 = fma4(z2, wvv, va2); va3 = fma4(z3, wvv, va3);
    }
    float kacc[16] = {ka0.x,ka0.y,ka0.z,ka0.w, ka1.x,ka1.y,ka1.z,ka1.w,
                      ka2.x,ka2.y,ka2.z,ka2.w, ka3.x,ka3.y,ka3.z,ka3.w};
    float vacc[16] = {va0.x,va0.y,va0.z,va0.w, va1.x,va1.y,va1.z,va1.w,
                      va2.x,va2.y,va2.z,va2.w, va3.x,va3.y,va3.z,va3.w};
    __syncthreads();   // all zt reads done; reuse zt region as vtmp

    float (*vtmp)[65] = (float(*)[65])&zt[0][0];
    const int key0 = kimg * 4096 + h * 64;
    float pe0 = sw[h] * A2[d] + cw[h] * B2[d] + F2[d];
    #pragma unroll
    for (int jj = 0; jj < 16; ++jj) {
        int j = wb + jj;
        float kv = kacc[jj] + pe0 + sw[j] * C2[d] + cw[j] * E2[d];
        int idx = (b * 16384 + key0 + j) * 64 + d;
        unsigned short hi = f2bf(kv);
        khi[idx] = hi;
        klo[idx] = f2bf(kv - bf2f(hi));
        vtmp[d][j] = vacc[jj] + vb[d];
    }
    __syncthreads();
    // packed transposed v store: thread -> (drow = tid>>2, 16 keys)
    {
        const int drow = tid >> 2, wc0 = (tid & 3) * 16;
        #pragma unroll
        for (int jj = 0; jj < 16; jj += 2) {
            unsigned int u = (unsigned int)f2bf(vtmp[drow][wc0 + jj]) |
                             ((unsigned int)f2bf(vtmp[drow][wc0 + jj + 1]) << 16);
            *(unsigned int*)&vt[(b * 64 + drow) * 16384 + key0 + wc0 + jj] = u;
        }
    }
}

// ---------------------------------------------------------------------------
// attn: grid 512 blocks x 512 threads. bid&7 -> (b,ks) 4096-key XCD slice,
// bid>>3 -> qblk (64 q-rows). 8 waves = 4 key-groups (1024 keys) x 2 q-waves
// (32 q-rows each). K (hi+lo) reg-staged to swizzled LDS (round-2-proven
// path; wave h stages component h). V read directly from global
// (L2-resident) - no LDS, no bank conflicts. exp2-domain softmax
// (q pre-scaled by log2e/8). Groups merge (m,l,acc) in LDS at epilogue.
// ---------------------------------------------------------------------------
__global__ __launch_bounds__(512, 4) void attn_kernel(
    const unsigned short* __restrict__ qhi, const unsigned short* __restrict__ qlo,
    const unsigned short* __restrict__ khi, const unsigned short* __restrict__ klo,
    const unsigned short* __restrict__ vt,
    float* __restrict__ accw, float* __restrict__ mlw)
{
    __shared__ __align__(16) unsigned short lds[32768]; // 64KB: [grp4][buf2][khi 2048 | klo 2048]
    const int tid = threadIdx.x;
    const int xcd = blockIdx.x & 7;
    const int qblk = blockIdx.x >> 3;       // 0..63
    const int b = xcd >> 2, ks = xcd & 3;
    const int lane = tid & 63, wv = tid >> 6;
    const int grp = wv >> 1;                // key-group 0..3
    const int h = wv & 1;                   // q-half 0..1
    const int l15 = lane & 15, g = lane >> 4;
    const int keybase = ks * 4096 + grp * 1024;

    // Q fragments: 2 q-tiles of 16 rows (pre-scaled by log2e/8)
    bf16x8 qh[2][2], ql[2][2];
    #pragma unroll
    for (int qt = 0; qt < 2; ++qt) {
        int qr = (b * 4096 + qblk * 64 + h * 32 + qt * 16 + l15) * 64;
        qh[qt][0] = *(const bf16x8*)&qhi[qr + 8 * g];
        qh[qt][1] = *(const bf16x8*)&qhi[qr + 32 + 8 * g];
        ql[qt][0] = *(const bf16x8*)&qlo[qr + 8 * g];
        ql[qt][1] = *(const bf16x8*)&qlo[qr + 32 + 8 * g];
    }

    // K staging (register -> swizzled ds_write_b128): wave h stages component h.
    // chunk p = j*64+lane (j=0..3): row = 8j + (lane>>3), col-chunk = lane&7,
    // LDS slot = chunk ^ (row&7); row&7 == lane>>3.
    const unsigned short* comp = h ? klo : khi;
    const int srow = lane >> 3, sc = lane & 7;
    const unsigned short* gk = comp + (b * 16384 + keybase + srow) * 64 + 8 * sc;
    const int sdst = srow * 64 + 8 * (sc ^ srow);        // + j*512 per chunk-row-block
    unsigned short* ldsc = lds + grp * 8192 + h * 2048;  // + buf*4096

    // V direct-from-global bases (per dt); advance 32 elems/iter
    const unsigned short* gv[4];
    #pragma unroll
    for (int dt = 0; dt < 4; ++dt)
        gv[dt] = vt + (size_t)(b * 64 + dt * 16 + l15) * 16384 + keybase + 4 * g;

    // swizzled K read offsets (ushort units within buf)
    int koff[2][2];
    #pragma unroll
    for (int rt = 0; rt < 2; ++rt) {
        int row = rt * 16 + l15;
        #pragma unroll
        for (int kc = 0; kc < 2; ++kc)
            koff[rt][kc] = row * 64 + 8 * ((4 * kc + g) ^ (row & 7));
    }

    // prologue: stage tile 0 -> buf 0
    {
        int4 t0 = *(const int4*)(gk);
        int4 t1 = *(const int4*)(gk + 512);
        int4 t2 = *(const int4*)(gk + 1024);
        int4 t3 = *(const int4*)(gk + 1536);
        *(int4*)&ldsc[sdst]        = t0;
        *(int4*)&ldsc[sdst + 512]  = t1;
        *(int4*)&ldsc[sdst + 1024] = t2;
        *(int4*)&ldsc[sdst + 1536] = t3;
    }
    __syncthreads();

    float m = -INFINITY, lsum = 0.f;
    f32x4 acc[2][4];
    #pragma unroll
    for (int qt = 0; qt < 2; ++qt)
        #pragma unroll
        for (int dt = 0; dt < 4; ++dt) acc[qt][dt] = (f32x4){0.f, 0.f, 0.f, 0.f};

    const int NIT = 32;   // 1024 keys / 32
    int buf = 0;
    for (int it = 0; it < NIT; ++it) {
        int4 n0, n1, n2, n3;
        const bool pf = (it + 1 < NIT);
        if (pf) {   // T14: issue next-tile loads early; write to LDS after compute
            const unsigned short* gn = gk + (it + 1) * 2048;
            n0 = *(const int4*)(gn);
            n1 = *(const int4*)(gn + 512);
            n2 = *(const int4*)(gn + 1024);
            n3 = *(const int4*)(gn + 1536);
        }
        const unsigned short* L = lds + grp * 8192 + buf * 4096;

        // QK^T (swapped): S'[key 16rt+4g+r][q l15], log2 units
        f32x4 c00 = {0,0,0,0}, c01 = {0,0,0,0}, c10 = {0,0,0,0}, c11 = {0,0,0,0};
        __builtin_amdgcn_s_setprio(1);
        {
            bf16x8 a0 = *(const bf16x8*)&L[koff[0][0]];
            bf16x8 a1 = *(const bf16x8*)&L[koff[0][1]];
            bf16x8 b0 = *(const bf16x8*)&L[2048 + koff[0][0]];
            bf16x8 b1 = *(const bf16x8*)&L[2048 + koff[0][1]];
            c00 = __builtin_amdgcn_mfma_f32_16x16x32_bf16(a0, qh[0][0], c00, 0, 0, 0);
            c00 = __builtin_amdgcn_mfma_f32_16x16x32_bf16(a1, qh[0][1], c00, 0, 0, 0);
            c00 = __builtin_amdgcn_mfma_f32_16x16x32_bf16(a0, ql[0][0], c00, 0, 0, 0);
            c00 = __builtin_amdgcn_mfma_f32_16x16x32_bf16(a1, ql[0][1], c00, 0, 0, 0);
            c00 = __builtin_amdgcn_mfma_f32_16x16x32_bf16(b0, qh[0][0], c00, 0, 0, 0);
            c00 = __builtin_amdgcn_mfma_f32_16x16x32_bf16(b1, qh[0][1], c00, 0, 0, 0);
            c10 = __builtin_amdgcn_mfma_f32_16x16x32_bf16(a0, qh[1][0], c10, 0, 0, 0);
            c10 = __builtin_amdgcn_mfma_f32_16x16x32_bf16(a1, qh[1][1], c10, 0, 0, 0);
            c10 = __builtin_amdgcn_mfma_f32_16x16x32_bf16(a0, ql[1][0], c10, 0, 0, 0);
            c10 = __builtin_amdgcn_mfma_f32_16x16x32_bf16(a1, ql[1][1], c10, 0, 0, 0);
            c10 = __builtin_amdgcn_mfma_f32_16x16x32_bf16(b0, qh[1][0], c10, 0, 0, 0);
            c10 = __builtin_amdgcn_mfma_f32_16x16x32_bf16(b1, qh[1][1], c10, 0, 0, 0);
        }
        {
            bf16x8 a0 = *(const bf16x8*)&L[koff[1][0]];
            bf16x8 a1 = *(const bf16x8*)&L[koff[1][1]];
            bf16x8 b0 = *(const bf16x8*)&L[2048 + koff[1][0]];
            bf16x8 b1 = *(const bf16x8*)&L[2048 + koff[1][1]];
            c01 = __builtin_amdgcn_mfma_f32_16x16x32_bf16(a0, qh[0][0], c01, 0, 0, 0);
            c01 = __builtin_amdgcn_mfma_f32_16x16x32_bf16(a1, qh[0][1], c01, 0, 0, 0);
            c01 = __builtin_amdgcn_mfma_f32_16x16x32_bf16(a0, ql[0][0], c01, 0, 0, 0);
            c01 = __builtin_amdgcn_mfma_f32_16x16x32_bf16(a1, ql[0][1], c01, 0, 0, 0);
            c01 = __builtin_amdgcn_mfma_f32_16x16x32_bf16(b0, qh[0][0], c01, 0, 0, 0);
            c01 = __builtin_amdgcn_mfma_f32_16x16x32_bf16(b1, qh[0][1], c01, 0, 0, 0);
            c11 = __builtin_amdgcn_mfma_f32_16x16x32_bf16(a0, qh[1][0], c11, 0, 0, 0);
            c11 = __builtin_amdgcn_mfma_f32_16x16x32_bf16(a1, qh[1][1], c11, 0, 0, 0);
            c11 = __builtin_amdgcn_mfma_f32_16x16x32_bf16(a0, ql[1][0], c11, 0, 0, 0);
            c11 = __builtin_amdgcn_mfma_f32_16x16x32_bf16(a1, ql[1][1], c11, 0, 0, 0);
            c11 = __builtin_amdgcn_mfma_f32_16x16x32_bf16(b0, qh[1][0], c11, 0, 0, 0);
            c11 = __builtin_amdgcn_mfma_f32_16x16x32_bf16(b1, qh[1][1], c11, 0, 0, 0);
        }
        __builtin_amdgcn_s_setprio(0);

        // V fragments for this tile, direct from global (L2-resident)
        bf16x4 va[4], vbx[4];
        #pragma unroll
        for (int dt = 0; dt < 4; ++dt) {
            const unsigned short* p = gv[dt];
            va[dt]  = *(const bf16x4*)p;          // keys 4g..4g+3
            vbx[dt] = *(const bf16x4*)(p + 16);   // keys 16+4g..+3
            gv[dt] += 32;
        }

        // softmax in log2 domain
        float s[16] = {c00[0],c00[1],c00[2],c00[3], c01[0],c01[1],c01[2],c01[3],
                       c10[0],c10[1],c10[2],c10[3], c11[0],c11[1],c11[2],c11[3]};
        float pmax = fmaxf(
            fmaxf(fmaxf(fmaxf(s[0],s[1]),fmaxf(s[2],s[3])), fmaxf(fmaxf(s[4],s[5]),fmaxf(s[6],s[7]))),
            fmaxf(fmaxf(fmaxf(s[8],s[9]),fmaxf(s[10],s[11])), fmaxf(fmaxf(s[12],s[13]),fmaxf(s[14],s[15]))));
        if (!__all(pmax <= m + 11.5f)) {    // T13 defer-max, THR = 8 nats
            float tmax = pmax;
            #pragma unroll
            for (int off = 1; off < 64; off <<= 1) tmax = fmaxf(tmax, __shfl_xor(tmax, off, 64));
            if (tmax > m) {
                float fac = exp2f(m - tmax);
                m = tmax; lsum *= fac;
                #pragma unroll
                for (int qt = 0; qt < 2; ++qt)
                    #pragma unroll
                    for (int dt = 0; dt < 4; ++dt) {
                        acc[qt][dt][0] *= fac; acc[qt][dt][1] *= fac;
                        acc[qt][dt][2] *= fac; acc[qt][dt][3] *= fac;
                    }
            }
        }
        float p[16];
        #pragma unroll
        for (int i = 0; i < 16; ++i) p[i] = exp2f(s[i] - m);
        float ps = ((p[0]+p[1])+(p[2]+p[3])) + ((p[4]+p[5])+(p[6]+p[7]))
                 + ((p[8]+p[9])+(p[10]+p[11])) + ((p[12]+p[13])+(p[14]+p[15]));
        lsum += ps;
        union { unsigned int u[8]; struct { bf16x8 a, b; } v; } pk;
        asm("v_cvt_pk_bf16_f32 %0, %1, %2" : "=v"(pk.u[0]) : "v"(p[0]),  "v"(p[1]));
        asm("v_cvt_pk_bf16_f32 %0, %1, %2" : "=v"(pk.u[1]) : "v"(p[2]),  "v"(p[3]));
        asm("v_cvt_pk_bf16_f32 %0, %1, %2" : "=v"(pk.u[2]) : "v"(p[4]),  "v"(p[5]));
        asm("v_cvt_pk_bf16_f32 %0, %1, %2" : "=v"(pk.u[3]) : "v"(p[6]),  "v"(p[7]));
        asm("v_cvt_pk_bf16_f32 %0, %1, %2" : "=v"(pk.u[4]) : "v"(p[8]),  "v"(p[9]));
        asm("v_cvt_pk_bf16_f32 %0, %1, %2" : "=v"(pk.u[5]) : "v"(p[10]), "v"(p[11]));
        asm("v_cvt_pk_bf16_f32 %0, %1, %2" : "=v"(pk.u[6]) : "v"(p[12]), "v"(p[13]));
        asm("v_cvt_pk_bf16_f32 %0, %1, %2" : "=v"(pk.u[7]) : "v"(p[14]), "v"(p[15]));

        // PV: acc[qt][dt] += pa[qt] x vf[dt]
        __builtin_amdgcn_s_setprio(1);
        #pragma unroll
        for (int dt = 0; dt < 4; ++dt) {
            bf16x8 vf = {va[dt][0], va[dt][1], va[dt][2], va[dt][3],
                         vbx[dt][0], vbx[dt][1], vbx[dt][2], vbx[dt][3]};
            acc[0][dt] = __builtin_amdgcn_mfma_f32_16x16x32_bf16(pk.v.a, vf, acc[0][dt], 0, 0, 0);
            acc[1][dt] = __builtin_amdgcn_mfma_f32_16x16x32_bf16(pk.v.b, vf, acc[1][dt], 0, 0, 0);
        }
        __builtin_amdgcn_s_setprio(0);

        if (pf) {   // write prefetched K tile into other buffer
            unsigned short* D = ldsc + (buf ^ 1) * 4096;
            *(int4*)&D[sdst]        = n0;
            *(int4*)&D[sdst + 512]  = n1;
            *(int4*)&D[sdst + 1024] = n2;
            *(int4*)&D[sdst + 1536] = n3;
        }
        __syncthreads();
        buf ^= 1;
    }

    // lane-reduce lsum (m is wave-uniform)
    #pragma unroll
    for (int off = 1; off < 64; off <<= 1) lsum += __shfl_xor(lsum, off, 64);

    // 4-group merge via LDS: groups 1-3 publish; group 0 merges + stores.
    // Publish slot wp = (grp-1)*2 + h; merging wave h reads wp = {h, 2+h, 4+h}.
    float* pub = (float*)lds;               // 6 waves x 2048 floats = 48KB
    float* mlp = pub + 12288;               // 12 floats (m,l per publishing wave)
    if (grp > 0) {
        const int wp = (grp - 1) * 2 + h;
        float* P = pub + wp * 2048;
        #pragma unroll
        for (int qt = 0; qt < 2; ++qt)
            #pragma unroll
            for (int dt = 0; dt < 4; ++dt)
                #pragma unroll
                for (int r = 0; r < 4; ++r)
                    P[((qt * 4 + dt) * 4 + r) * 64 + lane] = acc[qt][dt][r];
        if (lane == 0) { mlp[wp * 2] = m; mlp[wp * 2 + 1] = lsum; }
    }
    __syncthreads();
    if (grp == 0) {
        float mg[3], lg[3];
        #pragma unroll
        for (int i = 0; i < 3; ++i) {
            mg[i] = mlp[(i * 2 + h) * 2];
            lg[i] = mlp[(i * 2 + h) * 2 + 1];
        }
        float M = fmaxf(fmaxf(m, mg[0]), fmaxf(mg[1], mg[2]));
        float f0 = exp2f(m - M);
        float fg0 = exp2f(mg[0] - M), fg1 = exp2f(mg[1] - M), fg2 = exp2f(mg[2] - M);
        float L = lsum * f0 + lg[0] * fg0 + lg[1] * fg1 + lg[2] * fg2;
        const int unit = ((b * 64 + qblk) * 4 + ks) * 2 + h;
        if (lane == 0) { mlw[2 * unit] = M; mlw[2 * unit + 1] = L; }
        float* ab = accw + (size_t)unit * 2048;
        const float* P0 = pub + (0 + h) * 2048;
        const float* P1 = pub + (2 + h) * 2048;
        const float* P2 = pub + (4 + h) * 2048;
        #pragma unroll
        for (int qt = 0; qt < 2; ++qt)
            #pragma unroll
            for (int dt = 0; dt < 4; ++dt)
                #pragma unroll
                for (int r = 0; r < 4; ++r) {
                    int sl = ((qt * 4 + dt) * 4 + r) * 64 + lane;
                    float v = acc[qt][dt][r] * f0
                            + P0[sl] * fg0 + P1[sl] * fg1 + P2[sl] * fg2;
                    ab[(qt * 16 + 4 * g + r) * 64 + dt * 16 + l15] = v;
                }
    }
}

// ---------------------------------------------------------------------------
// finalize: per batch M = max m_u, L = sum l_u 2^{m_u-M}; out = sum_ks acc*2^{m-M}/L
// units: ((b*64+qblk)*4+ks)*2+h, 32 rows x 64 d each. grid 128 = (b, qblk).
// ---------------------------------------------------------------------------
__global__ __launch_bounds__(256) void finalize_kernel(
    const float* __restrict__ accw, const float* __restrict__ mlw, float* __restrict__ out)
{
    const int b = blockIdx.x >> 6;
    const int qblk = blockIdx.x & 63;
    const int tid = threadIdx.x;
    __shared__ float red[256];
    const float* mlb = mlw + b * 1024;   // 512 units x 2

    float mloc = fmaxf(mlb[2 * tid], mlb[2 * (tid + 256)]);
    red[tid] = mloc; __syncthreads();
    for (int s = 128; s > 0; s >>= 1) {
        if (tid < s) red[tid] = fmaxf(red[tid], red[tid + s]);
        __syncthreads();
    }
    const float Mb = red[0];
    __syncthreads();
    float lloc = mlb[2 * tid + 1] * exp2f(mlb[2 * tid] - Mb)
               + mlb[2 * (tid + 256) + 1] * exp2f(mlb[2 * (tid + 256)] - Mb);
    red[tid] = lloc; __syncthreads();
    for (int s = 128; s > 0; s >>= 1) {
        if (tid < s) red[tid] += red[tid + s];
        __syncthreads();
    }
    const float invL = 1.0f / red[0];

    const int d = tid & 63, rg = tid >> 6;
    float scl[4][2];
    #pragma unroll
    for (int ks = 0; ks < 4; ++ks)
        #pragma unroll
        for (int hh = 0; hh < 2; ++hh) {
            int unit = ((b * 64 + qblk) * 4 + ks) * 2 + hh;
            scl[ks][hh] = exp2f(mlw[2 * unit] - Mb) * invL;
        }
    #pragma unroll
    for (int rr = 0; rr < 16; ++rr) {
        int lr = rg * 16 + rr;
        int hh = lr >> 5, r32 = lr & 31;
        float o = 0.f;
        #pragma unroll
        for (int ks = 0; ks < 4; ++ks) {
            size_t unit = ((size_t)(b * 64 + qblk) * 4 + ks) * 2 + hh;
            o = fmaf(accw[unit * 2048 + r32 * 64 + d], scl[ks][hh], o);
        }
        out[(b * 4096 + qblk * 64 + lr) * 64 + d] = o;
    }
}

// ---------------------------------------------------------------------------
extern "C" void kernel_launch(void* const* d_in, const int* in_sizes, int n_in,
                              void* d_out, int out_size, void* d_ws, size_t ws_size,
                              hipStream_t stream) {
    const float* zx   = (const float*)d_in[0];
    const float* zy   = (const float*)d_in[1];
    const float* q_w  = (const float*)d_in[2];
    const float* q_b  = (const float*)d_in[3];
    const float* px_w = (const float*)d_in[4];
    const float* px_b = (const float*)d_in[5];
    const float* k_w  = (const float*)d_in[6];
    const float* k_b  = (const float*)d_in[7];
    const float* py_w = (const float*)d_in[8];
    const float* py_b = (const float*)d_in[9];
    const float* v_w  = (const float*)d_in[10];
    const float* v_b  = (const float*)d_in[11];

    unsigned short* qhi = (unsigned short*)d_ws;          // [2][4096][64]
    unsigned short* qlo = qhi + 524288;                   // [2][4096][64]
    unsigned short* khi = qlo + 524288;                   // [2][16384][64]
    unsigned short* klo = khi + 2097152;                  // [2][16384][64]
    unsigned short* vt  = klo + 2097152;                  // [2][64][16384] (transposed)
    float* accw = (float*)(vt + 2097152);                 // [1024 units][32][64]
    float* mlw  = accw + 2097152;                         // [1024 units][2]
    float* out  = (float*)d_out;

    proj_q_kernel<<<128, 256, 0, stream>>>(zx, q_w, q_b, px_w, px_b, qhi, qlo);
    proj_kv_kernel<<<512, 256, 0, stream>>>(zy, k_w, k_b, py_w, py_b, v_w, v_b, khi, klo, vt);
    attn_kernel<<<512, 512, 0, stream>>>(qhi, qlo, khi, klo, vt, accw, mlw);
    finalize_kernel<<<128, 256, 0, stream>>>(accw, mlw, out);
}

// Round 5
// 192.690 us; speedup vs baseline: 1.0174x; 1.0174x over previous
//
#include <hip/hip_runtime.h>
#include <hip/hip_bf16.h>
#include <stdint.h>

typedef short bf16x8 __attribute__((ext_vector_type(8)));
typedef short bf16x4 __attribute__((ext_vector_type(4)));
typedef float f32x4  __attribute__((ext_vector_type(4)));

__device__ __forceinline__ unsigned short f2bf(float x) {
    unsigned int u = __float_as_uint(x);
    unsigned int r = (u + 0x7fffu + ((u >> 16) & 1u)) >> 16;
    return (unsigned short)r;
}
__device__ __forceinline__ float bf2f(unsigned short h) {
    return __uint_as_float(((unsigned int)h) << 16);
}
__device__ __forceinline__ float4 fma4(float4 z, float s, float4 a) {
    a.x = fmaf(z.x, s, a.x); a.y = fmaf(z.y, s, a.y);
    a.z = fmaf(z.z, s, a.z); a.w = fmaf(z.w, s, a.w);
    return a;
}

// q pre-scale: (1/sqrt(64)) * log2(e)  -> scores come out in log2 units
#define QSCALE 0.18033688f

// ---------------------------------------------------------------------------
// proj_q: q[b, i*64+j, d] = (zx@qw + qb + PE·pxw + pxb) * 0.125*log2e
// PE collapses: sin(4i)*A[d] + cos(4i)*B[d] + sin(4j)*C[d] + cos(4j)*E[d] + F[d]
// grid 128 = (b, i). Output: split bf16 (hi, lo), pre-scaled.
// ---------------------------------------------------------------------------
__global__ __launch_bounds__(256) void proj_q_kernel(
    const float* __restrict__ zx, const float* __restrict__ qw, const float* __restrict__ qb,
    const float* __restrict__ pxw, const float* __restrict__ pxb,
    unsigned short* __restrict__ qhi, unsigned short* __restrict__ qlo)
{
    const int b = blockIdx.x >> 6;
    const int i = blockIdx.x & 63;
    const int tid = threadIdx.x;
    __shared__ __align__(16) float zt[64][68];
    __shared__ __align__(16) float wt[64][68];
    __shared__ float Af[64], Bf[64], Cf[64], Ef[64], Ff[64], sw[64], cw[64];

    {
        const int w = tid & 63, c0 = tid >> 6;
        #pragma unroll
        for (int cc = 0; cc < 16; ++cc) {
            int c = cc * 4 + c0;
            zt[c][w] = zx[((b * 64 + c) * 64 + i) * 64 + w];
        }
        #pragma unroll
        for (int ii = 0; ii < 16; ++ii) {
            int idx = tid + 256 * ii;
            wt[idx >> 6][idx & 63] = qw[idx];
        }
    }
    if (tid < 64) {
        int d = tid;
        float A = 0.f;
        for (int c = 0; c < 16; ++c) A += pxw[c * 64 + d];
        float F = 0.f;
        for (int c = 19; c < 64; ++c) F += pxw[c * 64 + d];
        Af[d] = A; Bf[d] = pxw[16 * 64 + d]; Cf[d] = pxw[17 * 64 + d]; Ef[d] = pxw[18 * 64 + d];
        Ff[d] = F + pxb[d] + qb[d];
        sw[d] = sinf(4.0f * (float)d); cw[d] = cosf(4.0f * (float)d);
    }
    __syncthreads();

    const int d = tid & 63, wb = (tid >> 6) * 16;
    float4 a0 = {0,0,0,0}, a1 = {0,0,0,0}, a2 = {0,0,0,0}, a3 = {0,0,0,0};
    for (int c = 0; c < 64; ++c) {
        float wvv = wt[c][d];
        const float4* zp = (const float4*)&zt[c][wb];
        a0 = fma4(zp[0], wvv, a0); a1 = fma4(zp[1], wvv, a1);
        a2 = fma4(zp[2], wvv, a2); a3 = fma4(zp[3], wvv, a3);
    }
    float acc[16] = {a0.x,a0.y,a0.z,a0.w, a1.x,a1.y,a1.z,a1.w,
                     a2.x,a2.y,a2.z,a2.w, a3.x,a3.y,a3.z,a3.w};
    float pe0 = sw[i] * Af[d] + cw[i] * Bf[d] + Ff[d];
    #pragma unroll
    for (int jj = 0; jj < 16; ++jj) {
        int j = wb + jj;
        float val = (acc[jj] + pe0 + sw[j] * Cf[d] + cw[j] * Ef[d]) * QSCALE;
        int idx = (b * 4096 + i * 64 + j) * 64 + d;
        unsigned short hi = f2bf(val);
        qhi[idx] = hi;
        qlo[idx] = f2bf(val - bf2f(hi));
    }
}

// ---------------------------------------------------------------------------
// proj_kv: k = zy@kw + kb + PE·pyw + pyb  (split bf16, [B][16384][64])
//          v = zy@vw + vb                 (bf16, TRANSPOSED [B][64][16384])
// grid 512 = (b, kimg, h).
// ---------------------------------------------------------------------------
__global__ __launch_bounds__(256) void proj_kv_kernel(
    const float* __restrict__ zy,
    const float* __restrict__ kw, const float* __restrict__ kb_,
    const float* __restrict__ pyw, const float* __restrict__ pyb,
    const float* __restrict__ vw, const float* __restrict__ vb_,
    unsigned short* __restrict__ khi, unsigned short* __restrict__ klo,
    unsigned short* __restrict__ vt)
{
    const int bk = blockIdx.x >> 6;     // 0..7
    const int b = bk >> 2, kimg = bk & 3;
    const int h = blockIdx.x & 63;
    const int tid = threadIdx.x;
    __shared__ __align__(16) float zt[64][68];
    __shared__ __align__(16) float kwt[64][68];
    __shared__ __align__(16) float vwt[64][68];
    __shared__ float A2[64], B2[64], C2[64], E2[64], F2[64], vb[64], sw[64], cw[64];

    {
        const int w = tid & 63, c0 = tid >> 6;
        #pragma unroll
        for (int cc = 0; cc < 16; ++cc) {
            int c = cc * 4 + c0;
            zt[c][w] = zy[(((b * 4 + kimg) * 64 + c) * 64 + h) * 64 + w];
        }
        #pragma unroll
        for (int ii = 0; ii < 16; ++ii) {
            int idx = tid + 256 * ii;
            kwt[idx >> 6][idx & 63] = kw[idx];
            vwt[idx >> 6][idx & 63] = vw[idx];
        }
    }
    if (tid < 64) {
        int d = tid;
        float A = 0.f;
        for (int c = 0; c < 16; ++c) A += pyw[c * 64 + d];
        float F = 0.f;
        for (int c = 19; c < 64; ++c) F += pyw[c * 64 + d];
        A2[d] = A; B2[d] = pyw[16 * 64 + d]; C2[d] = pyw[17 * 64 + d]; E2[d] = pyw[18 * 64 + d];
        F2[d] = F + pyb[d] + kb_[d];
        vb[d] = vb_[d];
        sw[d] = sinf(4.0f * (float)d); cw[d] = cosf(4.0f * (float)d);
    }
    __syncthreads();

    const int d = tid & 63, wb = (tid >> 6) * 16;
    float4 ka0 = {0,0,0,0}, ka1 = {0,0,0,0}, ka2 = {0,0,0,0}, ka3 = {0,0,0,0};
    float4 va0 = {0,0,0,0}, va1 = {0,0,0,0}, va2 = {0,0,0,0}, va3 = {0,0,0,0};
    for (int c = 0; c < 64; ++c) {
        float wk = kwt[c][d], wvv = vwt[c][d];
        const float4* zp = (const float4*)&zt[c][wb];
        float4 z0 = zp[0], z1 = zp[1], z2 = zp[2], z3 = zp[3];
        ka0 = fma4(z0, wk, ka0); ka1 = fma4(z1, wk, ka1);
        ka2 = fma4(z2, wk, ka2); ka3 = fma4(z3, wk, ka3);
        va0 = fma4(z0, wvv, va0); va1 = fma4(z1, wvv, va1);
        va2 = fma4(z2, wvv, va2); va3 = fma4(z3, wvv, va3);
    }
    float kacc[16] = {ka0.x,ka0.y,ka0.z,ka0.w, ka1.x,ka1.y,ka1.z,ka1.w,
                      ka2.x,ka2.y,ka2.z,ka2.w, ka3.x,ka3.y,ka3.z,ka3.w};
    float vacc[16] = {va0.x,va0.y,va0.z,va0.w, va1.x,va1.y,va1.z,va1.w,
                      va2.x,va2.y,va2.z,va2.w, va3.x,va3.y,va3.z,va3.w};
    __syncthreads();   // all zt reads done; reuse zt region as vtmp

    float (*vtmp)[65] = (float(*)[65])&zt[0][0];
    const int key0 = kimg * 4096 + h * 64;
    float pe0 = sw[h] * A2[d] + cw[h] * B2[d] + F2[d];
    #pragma unroll
    for (int jj = 0; jj < 16; ++jj) {
        int j = wb + jj;
        float kv = kacc[jj] + pe0 + sw[j] * C2[d] + cw[j] * E2[d];
        int idx = (b * 16384 + key0 + j) * 64 + d;
        unsigned short hi = f2bf(kv);
        khi[idx] = hi;
        klo[idx] = f2bf(kv - bf2f(hi));
        vtmp[d][j] = vacc[jj] + vb[d];
    }
    __syncthreads();
    // packed transposed v store: thread -> (drow = tid>>2, 16 keys)
    {
        const int drow = tid >> 2, wc0 = (tid & 3) * 16;
        #pragma unroll
        for (int jj = 0; jj < 16; jj += 2) {
            unsigned int u = (unsigned int)f2bf(vtmp[drow][wc0 + jj]) |
                             ((unsigned int)f2bf(vtmp[drow][wc0 + jj + 1]) << 16);
            *(unsigned int*)&vt[(b * 64 + drow) * 16384 + key0 + wc0 + jj] = u;
        }
    }
}

// ---------------------------------------------------------------------------
// attn: grid 512 blocks x 512 threads. bid&7 -> (b,ks) 4096-key XCD slice,
// bid>>3 -> qblk (64 q-rows). 8 waves = 4 key-groups (1024 keys) x 2 q-waves
// (32 q-rows each). K reg-staged to swizzled LDS; V direct from global
// (L2-resident). Register-dieted: K-prefetch issued AFTER QK^T (not live
// across the K-frag peak), V addressed via one 32-bit offset (saddr-form).
// Fits 128 unified regs @ 4 waves/SIMD -> no scratch spill.
// ---------------------------------------------------------------------------
__global__ __launch_bounds__(512, 4) void attn_kernel(
    const unsigned short* __restrict__ qhi, const unsigned short* __restrict__ qlo,
    const unsigned short* __restrict__ khi, const unsigned short* __restrict__ klo,
    const unsigned short* __restrict__ vt,
    float* __restrict__ accw, float* __restrict__ mlw)
{
    __shared__ __align__(16) unsigned short lds[32768]; // 64KB: [grp4][buf2][khi 2048 | klo 2048]
    const int tid = threadIdx.x;
    const int xcd = blockIdx.x & 7;
    const int qblk = blockIdx.x >> 3;       // 0..63
    const int b = xcd >> 2, ks = xcd & 3;
    const int lane = tid & 63, wv = tid >> 6;
    const int grp = wv >> 1;                // key-group 0..3
    const int h = wv & 1;                   // q-half 0..1
    const int l15 = lane & 15, g = lane >> 4;
    const int keybase = ks * 4096 + grp * 1024;

    // Q fragments: 2 q-tiles of 16 rows (pre-scaled by log2e/8)
    bf16x8 qh[2][2], ql[2][2];
    #pragma unroll
    for (int qt = 0; qt < 2; ++qt) {
        int qr = (b * 4096 + qblk * 64 + h * 32 + qt * 16 + l15) * 64;
        qh[qt][0] = *(const bf16x8*)&qhi[qr + 8 * g];
        qh[qt][1] = *(const bf16x8*)&qhi[qr + 32 + 8 * g];
        ql[qt][0] = *(const bf16x8*)&qlo[qr + 8 * g];
        ql[qt][1] = *(const bf16x8*)&qlo[qr + 32 + 8 * g];
    }

    // K staging (register -> swizzled ds_write_b128): wave h stages component h.
    const unsigned short* comp = h ? klo : khi;
    const int srow = lane >> 3, sc = lane & 7;
    const unsigned short* gk = comp + (b * 16384 + keybase + srow) * 64 + 8 * sc;
    const int sdst = srow * 64 + 8 * (sc ^ srow);        // + j*512 per chunk-row-block
    unsigned short* ldsc = lds + grp * 8192 + h * 2048;  // + buf*4096

    // V direct-from-global: single 32-bit element offset (saddr-form loads);
    // per-dt delta = dt*16*16384 = dt*262144 (compile-time), per-iter += 32.
    int koffv = (b * 64 + l15) * 16384 + keybase + 4 * g;

    // swizzled K read offsets (ushort units within buf)
    int koff[2][2];
    #pragma unroll
    for (int rt = 0; rt < 2; ++rt) {
        int row = rt * 16 + l15;
        #pragma unroll
        for (int kc = 0; kc < 2; ++kc)
            koff[rt][kc] = row * 64 + 8 * ((4 * kc + g) ^ (row & 7));
    }

    // prologue: stage tile 0 -> buf 0
    {
        int4 t0 = *(const int4*)(gk);
        int4 t1 = *(const int4*)(gk + 512);
        int4 t2 = *(const int4*)(gk + 1024);
        int4 t3 = *(const int4*)(gk + 1536);
        *(int4*)&ldsc[sdst]        = t0;
        *(int4*)&ldsc[sdst + 512]  = t1;
        *(int4*)&ldsc[sdst + 1024] = t2;
        *(int4*)&ldsc[sdst + 1536] = t3;
    }
    gk += 2048;
    __syncthreads();

    float m = -INFINITY, lsum = 0.f;
    f32x4 acc[2][4];
    #pragma unroll
    for (int qt = 0; qt < 2; ++qt)
        #pragma unroll
        for (int dt = 0; dt < 4; ++dt) acc[qt][dt] = (f32x4){0.f, 0.f, 0.f, 0.f};

    const int NIT = 32;   // 1024 keys / 32
    int buf = 0;
    for (int it = 0; it < NIT; ++it) {
        const unsigned short* L = lds + grp * 8192 + buf * 4096;

        // ---- QK^T (swapped): S'[key 16rt+4g+r][q l15], log2 units ----
        f32x4 c00 = {0,0,0,0}, c01 = {0,0,0,0}, c10 = {0,0,0,0}, c11 = {0,0,0,0};
        __builtin_amdgcn_s_setprio(1);
        {
            bf16x8 a0 = *(const bf16x8*)&L[koff[0][0]];
            bf16x8 a1 = *(const bf16x8*)&L[koff[0][1]];
            bf16x8 b0 = *(const bf16x8*)&L[2048 + koff[0][0]];
            bf16x8 b1 = *(const bf16x8*)&L[2048 + koff[0][1]];
            c00 = __builtin_amdgcn_mfma_f32_16x16x32_bf16(a0, qh[0][0], c00, 0, 0, 0);
            c00 = __builtin_amdgcn_mfma_f32_16x16x32_bf16(a1, qh[0][1], c00, 0, 0, 0);
            c00 = __builtin_amdgcn_mfma_f32_16x16x32_bf16(a0, ql[0][0], c00, 0, 0, 0);
            c00 = __builtin_amdgcn_mfma_f32_16x16x32_bf16(a1, ql[0][1], c00, 0, 0, 0);
            c00 = __builtin_amdgcn_mfma_f32_16x16x32_bf16(b0, qh[0][0], c00, 0, 0, 0);
            c00 = __builtin_amdgcn_mfma_f32_16x16x32_bf16(b1, qh[0][1], c00, 0, 0, 0);
            c10 = __builtin_amdgcn_mfma_f32_16x16x32_bf16(a0, qh[1][0], c10, 0, 0, 0);
            c10 = __builtin_amdgcn_mfma_f32_16x16x32_bf16(a1, qh[1][1], c10, 0, 0, 0);
            c10 = __builtin_amdgcn_mfma_f32_16x16x32_bf16(a0, ql[1][0], c10, 0, 0, 0);
            c10 = __builtin_amdgcn_mfma_f32_16x16x32_bf16(a1, ql[1][1], c10, 0, 0, 0);
            c10 = __builtin_amdgcn_mfma_f32_16x16x32_bf16(b0, qh[1][0], c10, 0, 0, 0);
            c10 = __builtin_amdgcn_mfma_f32_16x16x32_bf16(b1, qh[1][1], c10, 0, 0, 0);
        }
        {
            bf16x8 a0 = *(const bf16x8*)&L[koff[1][0]];
            bf16x8 a1 = *(const bf16x8*)&L[koff[1][1]];
            bf16x8 b0 = *(const bf16x8*)&L[2048 + koff[1][0]];
            bf16x8 b1 = *(const bf16x8*)&L[2048 + koff[1][1]];
            c01 = __builtin_amdgcn_mfma_f32_16x16x32_bf16(a0, qh[0][0], c01, 0, 0, 0);
            c01 = __builtin_amdgcn_mfma_f32_16x16x32_bf16(a1, qh[0][1], c01, 0, 0, 0);
            c01 = __builtin_amdgcn_mfma_f32_16x16x32_bf16(a0, ql[0][0], c01, 0, 0, 0);
            c01 = __builtin_amdgcn_mfma_f32_16x16x32_bf16(a1, ql[0][1], c01, 0, 0, 0);
            c01 = __builtin_amdgcn_mfma_f32_16x16x32_bf16(b0, qh[0][0], c01, 0, 0, 0);
            c01 = __builtin_amdgcn_mfma_f32_16x16x32_bf16(b1, qh[0][1], c01, 0, 0, 0);
            c11 = __builtin_amdgcn_mfma_f32_16x16x32_bf16(a0, qh[1][0], c11, 0, 0, 0);
            c11 = __builtin_amdgcn_mfma_f32_16x16x32_bf16(a1, qh[1][1], c11, 0, 0, 0);
            c11 = __builtin_amdgcn_mfma_f32_16x16x32_bf16(a0, ql[1][0], c11, 0, 0, 0);
            c11 = __builtin_amdgcn_mfma_f32_16x16x32_bf16(a1, ql[1][1], c11, 0, 0, 0);
            c11 = __builtin_amdgcn_mfma_f32_16x16x32_bf16(b0, qh[1][0], c11, 0, 0, 0);
            c11 = __builtin_amdgcn_mfma_f32_16x16x32_bf16(b1, qh[1][1], c11, 0, 0, 0);
        }
        __builtin_amdgcn_s_setprio(0);

        // ---- issue V loads (needed at PV, ~300cyc away under softmax) ----
        bf16x4 va[4], vbx[4];
        #pragma unroll
        for (int dt = 0; dt < 4; ++dt) {
            const unsigned short* p = vt + koffv + dt * 262144;
            va[dt]  = *(const bf16x4*)p;          // keys 4g..4g+3
            vbx[dt] = *(const bf16x4*)(p + 16);   // keys 16+4g..+3
        }
        koffv += 32;

        // ---- issue K prefetch (needed at ds_write, after PV) ----
        int4 n0, n1, n2, n3;
        const bool pf = (it + 1 < NIT);
        if (pf) {
            n0 = *(const int4*)(gk);
            n1 = *(const int4*)(gk + 512);
            n2 = *(const int4*)(gk + 1024);
            n3 = *(const int4*)(gk + 1536);
        }
        gk += 2048;

        // ---- softmax in log2 domain ----
        float pmax = fmaxf(
            fmaxf(fmaxf(fmaxf(c00[0],c00[1]),fmaxf(c00[2],c00[3])),
                  fmaxf(fmaxf(c01[0],c01[1]),fmaxf(c01[2],c01[3]))),
            fmaxf(fmaxf(fmaxf(c10[0],c10[1]),fmaxf(c10[2],c10[3])),
                  fmaxf(fmaxf(c11[0],c11[1]),fmaxf(c11[2],c11[3]))));
        if (!__all(pmax <= m + 11.5f)) {    // T13 defer-max, THR = 8 nats
            float tmax = pmax;
            #pragma unroll
            for (int off = 1; off < 64; off <<= 1) tmax = fmaxf(tmax, __shfl_xor(tmax, off, 64));
            if (tmax > m) {
                float fac = exp2f(m - tmax);
                m = tmax; lsum *= fac;
                #pragma unroll
                for (int qt = 0; qt < 2; ++qt)
                    #pragma unroll
                    for (int dt = 0; dt < 4; ++dt) {
                        acc[qt][dt][0] *= fac; acc[qt][dt][1] *= fac;
                        acc[qt][dt][2] *= fac; acc[qt][dt][3] *= fac;
                    }
            }
        }
        float p0  = exp2f(c00[0] - m), p1  = exp2f(c00[1] - m);
        float p2  = exp2f(c00[2] - m), p3  = exp2f(c00[3] - m);
        float p4  = exp2f(c01[0] - m), p5  = exp2f(c01[1] - m);
        float p6  = exp2f(c01[2] - m), p7  = exp2f(c01[3] - m);
        float p8  = exp2f(c10[0] - m), p9  = exp2f(c10[1] - m);
        float p10 = exp2f(c10[2] - m), p11 = exp2f(c10[3] - m);
        float p12 = exp2f(c11[0] - m), p13 = exp2f(c11[1] - m);
        float p14 = exp2f(c11[2] - m), p15 = exp2f(c11[3] - m);
        lsum += ((p0+p1)+(p2+p3)) + ((p4+p5)+(p6+p7))
              + ((p8+p9)+(p10+p11)) + ((p12+p13)+(p14+p15));
        union { unsigned int u[8]; struct { bf16x8 a, b; } v; } pk;
        asm("v_cvt_pk_bf16_f32 %0, %1, %2" : "=v"(pk.u[0]) : "v"(p0),  "v"(p1));
        asm("v_cvt_pk_bf16_f32 %0, %1, %2" : "=v"(pk.u[1]) : "v"(p2),  "v"(p3));
        asm("v_cvt_pk_bf16_f32 %0, %1, %2" : "=v"(pk.u[2]) : "v"(p4),  "v"(p5));
        asm("v_cvt_pk_bf16_f32 %0, %1, %2" : "=v"(pk.u[3]) : "v"(p6),  "v"(p7));
        asm("v_cvt_pk_bf16_f32 %0, %1, %2" : "=v"(pk.u[4]) : "v"(p8),  "v"(p9));
        asm("v_cvt_pk_bf16_f32 %0, %1, %2" : "=v"(pk.u[5]) : "v"(p10), "v"(p11));
        asm("v_cvt_pk_bf16_f32 %0, %1, %2" : "=v"(pk.u[6]) : "v"(p12), "v"(p13));
        asm("v_cvt_pk_bf16_f32 %0, %1, %2" : "=v"(pk.u[7]) : "v"(p14), "v"(p15));

        // ---- PV: acc[qt][dt] += pa[qt] x vf[dt] ----
        __builtin_amdgcn_s_setprio(1);
        #pragma unroll
        for (int dt = 0; dt < 4; ++dt) {
            bf16x8 vf = {va[dt][0], va[dt][1], va[dt][2], va[dt][3],
                         vbx[dt][0], vbx[dt][1], vbx[dt][2], vbx[dt][3]};
            acc[0][dt] = __builtin_amdgcn_mfma_f32_16x16x32_bf16(pk.v.a, vf, acc[0][dt], 0, 0, 0);
            acc[1][dt] = __builtin_amdgcn_mfma_f32_16x16x32_bf16(pk.v.b, vf, acc[1][dt], 0, 0, 0);
        }
        __builtin_amdgcn_s_setprio(0);

        if (pf) {   // write prefetched K tile into other buffer
            unsigned short* D = ldsc + (buf ^ 1) * 4096;
            *(int4*)&D[sdst]        = n0;
            *(int4*)&D[sdst + 512]  = n1;
            *(int4*)&D[sdst + 1024] = n2;
            *(int4*)&D[sdst + 1536] = n3;
        }
        __syncthreads();
        buf ^= 1;
    }

    // lane-reduce lsum (m is wave-uniform)
    #pragma unroll
    for (int off = 1; off < 64; off <<= 1) lsum += __shfl_xor(lsum, off, 64);

    // 4-group merge via LDS: groups 1-3 publish; group 0 merges + stores.
    // Publish slot wp = (grp-1)*2 + h; merging wave h reads wp = {h, 2+h, 4+h}.
    float* pub = (float*)lds;               // 6 waves x 2048 floats = 48KB
    float* mlp = pub + 12288;               // 12 floats (m,l per publishing wave)
    if (grp > 0) {
        const int wp = (grp - 1) * 2 + h;
        float* P = pub + wp * 2048;
        #pragma unroll
        for (int qt = 0; qt < 2; ++qt)
            #pragma unroll
            for (int dt = 0; dt < 4; ++dt)
                #pragma unroll
                for (int r = 0; r < 4; ++r)
                    P[((qt * 4 + dt) * 4 + r) * 64 + lane] = acc[qt][dt][r];
        if (lane == 0) { mlp[wp * 2] = m; mlp[wp * 2 + 1] = lsum; }
    }
    __syncthreads();
    if (grp == 0) {
        float mg[3], lg[3];
        #pragma unroll
        for (int i = 0; i < 3; ++i) {
            mg[i] = mlp[(i * 2 + h) * 2];
            lg[i] = mlp[(i * 2 + h) * 2 + 1];
        }
        float M = fmaxf(fmaxf(m, mg[0]), fmaxf(mg[1], mg[2]));
        float f0 = exp2f(m - M);
        float fg0 = exp2f(mg[0] - M), fg1 = exp2f(mg[1] - M), fg2 = exp2f(mg[2] - M);
        float L = lsum * f0 + lg[0] * fg0 + lg[1] * fg1 + lg[2] * fg2;
        const int unit = ((b * 64 + qblk) * 4 + ks) * 2 + h;
        if (lane == 0) { mlw[2 * unit] = M; mlw[2 * unit + 1] = L; }
        float* ab = accw + (size_t)unit * 2048;
        const float* P0 = pub + (0 + h) * 2048;
        const float* P1 = pub + (2 + h) * 2048;
        const float* P2 = pub + (4 + h) * 2048;
        #pragma unroll
        for (int qt = 0; qt < 2; ++qt)
            #pragma unroll
            for (int dt = 0; dt < 4; ++dt)
                #pragma unroll
                for (int r = 0; r < 4; ++r) {
                    int sl = ((qt * 4 + dt) * 4 + r) * 64 + lane;
                    float v = acc[qt][dt][r] * f0
                            + P0[sl] * fg0 + P1[sl] * fg1 + P2[sl] * fg2;
                    ab[(qt * 16 + 4 * g + r) * 64 + dt * 16 + l15] = v;
                }
    }
}

// ---------------------------------------------------------------------------
// finalize: per batch M = max m_u, L = sum l_u 2^{m_u-M}; out = sum_ks acc*2^{m-M}/L
// units: ((b*64+qblk)*4+ks)*2+h, 32 rows x 64 d each. grid 128 = (b, qblk).
// ---------------------------------------------------------------------------
__global__ __launch_bounds__(256) void finalize_kernel(
    const float* __restrict__ accw, const float* __restrict__ mlw, float* __restrict__ out)
{
    const int b = blockIdx.x >> 6;
    const int qblk = blockIdx.x & 63;
    const int tid = threadIdx.x;
    __shared__ float red[256];
    const float* mlb = mlw + b * 1024;   // 512 units x 2

    float mloc = fmaxf(mlb[2 * tid], mlb[2 * (tid + 256)]);
    red[tid] = mloc; __syncthreads();
    for (int s = 128; s > 0; s >>= 1) {
        if (tid < s) red[tid] = fmaxf(red[tid], red[tid + s]);
        __syncthreads();
    }
    const float Mb = red[0];
    __syncthreads();
    float lloc = mlb[2 * tid + 1] * exp2f(mlb[2 * tid] - Mb)
               + mlb[2 * (tid + 256) + 1] * exp2f(mlb[2 * (tid + 256)] - Mb);
    red[tid] = lloc; __syncthreads();
    for (int s = 128; s > 0; s >>= 1) {
        if (tid < s) red[tid] += red[tid + s];
        __syncthreads();
    }
    const float invL = 1.0f / red[0];

    const int d = tid & 63, rg = tid >> 6;
    float scl[4][2];
    #pragma unroll
    for (int ks = 0; ks < 4; ++ks)
        #pragma unroll
        for (int hh = 0; hh < 2; ++hh) {
            int unit = ((b * 64 + qblk) * 4 + ks) * 2 + hh;
            scl[ks][hh] = exp2f(mlw[2 * unit] - Mb) * invL;
        }
    #pragma unroll
    for (int rr = 0; rr < 16; ++rr) {
        int lr = rg * 16 + rr;
        int hh = lr >> 5, r32 = lr & 31;
        float o = 0.f;
        #pragma unroll
        for (int ks = 0; ks < 4; ++ks) {
            size_t unit = ((size_t)(b * 64 + qblk) * 4 + ks) * 2 + hh;
            o = fmaf(accw[unit * 2048 + r32 * 64 + d], scl[ks][hh], o);
        }
        out[(b * 4096 + qblk * 64 + lr) * 64 + d] = o;
    }
}

// ---------------------------------------------------------------------------
extern "C" void kernel_launch(void* const* d_in, const int* in_sizes, int n_in,
                              void* d_out, int out_size, void* d_ws, size_t ws_size,
                              hipStream_t stream) {
    const float* zx   = (const float*)d_in[0];
    const float* zy   = (const float*)d_in[1];
    const float* q_w  = (const float*)d_in[2];
    const float* q_b  = (const float*)d_in[3];
    const float* px_w = (const float*)d_in[4];
    const float* px_b = (const float*)d_in[5];
    const float* k_w  = (const float*)d_in[6];
    const float* k_b  = (const float*)d_in[7];
    const float* py_w = (const float*)d_in[8];
    const float* py_b = (const float*)d_in[9];
    const float* v_w  = (const float*)d_in[10];
    const float* v_b  = (const float*)d_in[11];

    unsigned short* qhi = (unsigned short*)d_ws;          // [2][4096][64]
    unsigned short* qlo = qhi + 524288;                   // [2][4096][64]
    unsigned short* khi = qlo + 524288;                   // [2][16384][64]
    unsigned short* klo = khi + 2097152;                  // [2][16384][64]
    unsigned short* vt  = klo + 2097152;                  // [2][64][16384] (transposed)
    float* accw = (float*)(vt + 2097152);                 // [1024 units][32][64]
    float* mlw  = accw + 2097152;                         // [1024 units][2]
    float* out  = (float*)d_out;

    proj_q_kernel<<<128, 256, 0, stream>>>(zx, q_w, q_b, px_w, px_b, qhi, qlo);
    proj_kv_kernel<<<512, 256, 0, stream>>>(zy, k_w, k_b, py_w, py_b, v_w, v_b, khi, klo, vt);
    attn_kernel<<<512, 512, 0, stream>>>(qhi, qlo, khi, klo, vt, accw, mlw);
    finalize_kernel<<<128, 256, 0, stream>>>(accw, mlw, out);
}

// Round 8
// 140.408 us; speedup vs baseline: 1.3963x; 1.3724x over previous
//
#include <hip/hip_runtime.h>
#include <hip/hip_bf16.h>
#include <stdint.h>

typedef short bf16x8 __attribute__((ext_vector_type(8)));
typedef short bf16x4 __attribute__((ext_vector_type(4)));
typedef float f32x4  __attribute__((ext_vector_type(4)));

__device__ __forceinline__ unsigned short f2bf(float x) {
    unsigned int u = __float_as_uint(x);
    unsigned int r = (u + 0x7fffu + ((u >> 16) & 1u)) >> 16;
    return (unsigned short)r;
}
__device__ __forceinline__ float bf2f(unsigned short h) {
    return __uint_as_float(((unsigned int)h) << 16);
}
__device__ __forceinline__ float4 fma4(float4 z, float s, float4 a) {
    a.x = fmaf(z.x, s, a.x); a.y = fmaf(z.y, s, a.y);
    a.z = fmaf(z.z, s, a.z); a.w = fmaf(z.w, s, a.w);
    return a;
}

// q pre-scale: (1/sqrt(64)) * log2(e)  -> scores come out in log2 units
#define QSCALE 0.18033688f

// ---------------------------------------------------------------------------
// proj_q: q[b, i*64+j, d] = (zx@qw + qb + PE·pxw + pxb) * 0.125*log2e
// PE collapses: sin(4i)*A[d] + cos(4i)*B[d] + sin(4j)*C[d] + cos(4j)*E[d] + F[d]
// grid 128 = (b, i). Output: split bf16 (hi, lo), pre-scaled.
// ---------------------------------------------------------------------------
__global__ __launch_bounds__(256) void proj_q_kernel(
    const float* __restrict__ zx, const float* __restrict__ qw, const float* __restrict__ qb,
    const float* __restrict__ pxw, const float* __restrict__ pxb,
    unsigned short* __restrict__ qhi, unsigned short* __restrict__ qlo)
{
    const int b = blockIdx.x >> 6;
    const int i = blockIdx.x & 63;
    const int tid = threadIdx.x;
    __shared__ __align__(16) float zt[64][68];
    __shared__ __align__(16) float wt[64][68];
    __shared__ float Af[64], Bf[64], Cf[64], Ef[64], Ff[64], sw[64], cw[64];

    {
        const int w = tid & 63, c0 = tid >> 6;
        #pragma unroll
        for (int cc = 0; cc < 16; ++cc) {
            int c = cc * 4 + c0;
            zt[c][w] = zx[((b * 64 + c) * 64 + i) * 64 + w];
        }
        #pragma unroll
        for (int ii = 0; ii < 16; ++ii) {
            int idx = tid + 256 * ii;
            wt[idx >> 6][idx & 63] = qw[idx];
        }
    }
    if (tid < 64) {
        int d = tid;
        float A = 0.f;
        for (int c = 0; c < 16; ++c) A += pxw[c * 64 + d];
        float F = 0.f;
        for (int c = 19; c < 64; ++c) F += pxw[c * 64 + d];
        Af[d] = A; Bf[d] = pxw[16 * 64 + d]; Cf[d] = pxw[17 * 64 + d]; Ef[d] = pxw[18 * 64 + d];
        Ff[d] = F + pxb[d] + qb[d];
        sw[d] = sinf(4.0f * (float)d); cw[d] = cosf(4.0f * (float)d);
    }
    __syncthreads();

    const int d = tid & 63, wb = (tid >> 6) * 16;
    float4 a0 = {0,0,0,0}, a1 = {0,0,0,0}, a2 = {0,0,0,0}, a3 = {0,0,0,0};
    for (int c = 0; c < 64; ++c) {
        float wvv = wt[c][d];
        const float4* zp = (const float4*)&zt[c][wb];
        a0 = fma4(zp[0], wvv, a0); a1 = fma4(zp[1], wvv, a1);
        a2 = fma4(zp[2], wvv, a2); a3 = fma4(zp[3], wvv, a3);
    }
    float acc[16] = {a0.x,a0.y,a0.z,a0.w, a1.x,a1.y,a1.z,a1.w,
                     a2.x,a2.y,a2.z,a2.w, a3.x,a3.y,a3.z,a3.w};
    float pe0 = sw[i] * Af[d] + cw[i] * Bf[d] + Ff[d];
    #pragma unroll
    for (int jj = 0; jj < 16; ++jj) {
        int j = wb + jj;
        float val = (acc[jj] + pe0 + sw[j] * Cf[d] + cw[j] * Ef[d]) * QSCALE;
        int idx = (b * 4096 + i * 64 + j) * 64 + d;
        unsigned short hi = f2bf(val);
        qhi[idx] = hi;
        qlo[idx] = f2bf(val - bf2f(hi));
    }
}

// ---------------------------------------------------------------------------
// proj_kv: k = zy@kw + kb + PE·pyw + pyb  (split bf16, [B][16384][64])
//          v = zy@vw + vb                 (bf16, TRANSPOSED [B][64][16384])
// grid 512 = (b, kimg, h).
// ---------------------------------------------------------------------------
__global__ __launch_bounds__(256) void proj_kv_kernel(
    const float* __restrict__ zy,
    const float* __restrict__ kw, const float* __restrict__ kb_,
    const float* __restrict__ pyw, const float* __restrict__ pyb,
    const float* __restrict__ vw, const float* __restrict__ vb_,
    unsigned short* __restrict__ khi, unsigned short* __restrict__ klo,
    unsigned short* __restrict__ vt)
{
    const int bk = blockIdx.x >> 6;     // 0..7
    const int b = bk >> 2, kimg = bk & 3;
    const int h = blockIdx.x & 63;
    const int tid = threadIdx.x;
    __shared__ __align__(16) float zt[64][68];
    __shared__ __align__(16) float kwt[64][68];
    __shared__ __align__(16) float vwt[64][68];
    __shared__ float A2[64], B2[64], C2[64], E2[64], F2[64], vb[64], sw[64], cw[64];

    {
        const int w = tid & 63, c0 = tid >> 6;
        #pragma unroll
        for (int cc = 0; cc < 16; ++cc) {
            int c = cc * 4 + c0;
            zt[c][w] = zy[(((b * 4 + kimg) * 64 + c) * 64 + h) * 64 + w];
        }
        #pragma unroll
        for (int ii = 0; ii < 16; ++ii) {
            int idx = tid + 256 * ii;
            kwt[idx >> 6][idx & 63] = kw[idx];
            vwt[idx >> 6][idx & 63] = vw[idx];
        }
    }
    if (tid < 64) {
        int d = tid;
        float A = 0.f;
        for (int c = 0; c < 16; ++c) A += pyw[c * 64 + d];
        float F = 0.f;
        for (int c = 19; c < 64; ++c) F += pyw[c * 64 + d];
        A2[d] = A; B2[d] = pyw[16 * 64 + d]; C2[d] = pyw[17 * 64 + d]; E2[d] = pyw[18 * 64 + d];
        F2[d] = F + pyb[d] + kb_[d];
        vb[d] = vb_[d];
        sw[d] = sinf(4.0f * (float)d); cw[d] = cosf(4.0f * (float)d);
    }
    __syncthreads();

    const int d = tid & 63, wb = (tid >> 6) * 16;
    float4 ka0 = {0,0,0,0}, ka1 = {0,0,0,0}, ka2 = {0,0,0,0}, ka3 = {0,0,0,0};
    float4 va0 = {0,0,0,0}, va1 = {0,0,0,0}, va2 = {0,0,0,0}, va3 = {0,0,0,0};
    for (int c = 0; c < 64; ++c) {
        float wk = kwt[c][d], wvv = vwt[c][d];
        const float4* zp = (const float4*)&zt[c][wb];
        float4 z0 = zp[0], z1 = zp[1], z2 = zp[2], z3 = zp[3];
        ka0 = fma4(z0, wk, ka0); ka1 = fma4(z1, wk, ka1);
        ka2 = fma4(z2, wk, ka2); ka3 = fma4(z3, wk, ka3);
        va0 = fma4(z0, wvv, va0); va1 = fma4(z1, wvv, va1);
        va2 = fma4(z2, wvv, va2); va3 = fma4(z3, wvv, va3);
    }
    float kacc[16] = {ka0.x,ka0.y,ka0.z,ka0.w, ka1.x,ka1.y,ka1.z,ka1.w,
                      ka2.x,ka2.y,ka2.z,ka2.w, ka3.x,ka3.y,ka3.z,ka3.w};
    float vacc[16] = {va0.x,va0.y,va0.z,va0.w, va1.x,va1.y,va1.z,va1.w,
                      va2.x,va2.y,va2.z,va2.w, va3.x,va3.y,va3.z,va3.w};
    __syncthreads();   // all zt reads done; reuse zt region as vtmp

    float (*vtmp)[65] = (float(*)[65])&zt[0][0];
    const int key0 = kimg * 4096 + h * 64;
    float pe0 = sw[h] * A2[d] + cw[h] * B2[d] + F2[d];
    #pragma unroll
    for (int jj = 0; jj < 16; ++jj) {
        int j = wb + jj;
        float kv = kacc[jj] + pe0 + sw[j] * C2[d] + cw[j] * E2[d];
        int idx = (b * 16384 + key0 + j) * 64 + d;
        unsigned short hi = f2bf(kv);
        khi[idx] = hi;
        klo[idx] = f2bf(kv - bf2f(hi));
        vtmp[d][j] = vacc[jj] + vb[d];
    }
    __syncthreads();
    // packed transposed v store: thread -> (drow = tid>>2, 16 keys)
    {
        const int drow = tid >> 2, wc0 = (tid & 3) * 16;
        #pragma unroll
        for (int jj = 0; jj < 16; jj += 2) {
            unsigned int u = (unsigned int)f2bf(vtmp[drow][wc0 + jj]) |
                             ((unsigned int)f2bf(vtmp[drow][wc0 + jj + 1]) << 16);
            *(unsigned int*)&vt[(b * 64 + drow) * 16384 + key0 + wc0 + jj] = u;
        }
    }
}

// ---------------------------------------------------------------------------
// attn: grid 512 blocks x 512 threads (8 waves = 2 groups of 4).
// bid&7 -> (b,ks) slice (XCD L2-resident); bid>>3 -> qblk (64 q-rows).
// Group grp handles keys [ks*4096 + grp*2048, +2048) for the SAME 64 q-rows;
// groups merge (m,l,acc) via LDS at the epilogue. exp2-domain softmax
// (q pre-scaled by log2e/8).
// ---------------------------------------------------------------------------
__global__ __launch_bounds__(512, 4) void attn_kernel(
    const unsigned short* __restrict__ qhi, const unsigned short* __restrict__ qlo,
    const unsigned short* __restrict__ khi, const unsigned short* __restrict__ klo,
    const unsigned short* __restrict__ vt,
    float* __restrict__ accw, float* __restrict__ mlw)
{
    __shared__ __align__(16) unsigned short lds[2 * 2 * 6144]; // [grp][buf][khi 2048|klo 2048|v 2048]
    const int tid = threadIdx.x;
    const int tid8 = tid & 255;
    const int grp = tid >> 8;               // key-half group
    const int xcd = blockIdx.x & 7;
    const int qblk = blockIdx.x >> 3;       // 0..63
    const int b = xcd >> 2, ks = xcd & 3;
    const int lane = tid & 63, wv = (tid >> 6) & 3;
    const int l15 = lane & 15, g = lane >> 4;

    // q fragments (registers, whole kernel); q is pre-scaled by log2e/8
    bf16x8 qh[2], ql[2];
    {
        int qr = (b * 4096 + qblk * 64 + wv * 16 + l15) * 64;
        qh[0] = *(const bf16x8*)&qhi[qr + 8 * g];
        qh[1] = *(const bf16x8*)&qhi[qr + 32 + 8 * g];
        ql[0] = *(const bf16x8*)&qlo[qr + 8 * g];
        ql[1] = *(const bf16x8*)&qlo[qr + 32 + 8 * g];
    }

    unsigned short* GL = lds + grp * 12288;
    // staging: thread stages one 16B chunk per tile-component; XOR-swizzled slots
    const int trow = tid8 >> 3, tc = tid8 & 7;
    const int kdst = trow * 64 + 8 * (tc ^ (trow & 7));
    const int vd = tid8 >> 2, vs = tid8 & 3;
    const int vdst = 4096 + vd * 32 + 8 * (vs ^ ((vd >> 1) & 3));
    const int keybase = ks * 4096 + grp * 2048;
    const unsigned short* gkh = khi + (b * 16384 + keybase + trow) * 64 + 8 * tc;
    const unsigned short* gkl = klo + (b * 16384 + keybase + trow) * 64 + 8 * tc;
    const unsigned short* gv  = vt  + (b * 64 + vd) * 16384 + keybase + 8 * vs;

    { // prologue: stage tile 0 into buffer 0
        int4 a = *(const int4*)gkh;
        int4 c = *(const int4*)gkl;
        int4 v = *(const int4*)gv;
        *(int4*)&GL[kdst] = a;
        *(int4*)&GL[2048 + kdst] = c;
        *(int4*)&GL[vdst] = v;
    }
    __syncthreads();

    // fragment LDS read offsets (swizzle-matched)
    int koff[2][2], voff[4][2];
    #pragma unroll
    for (int rt = 0; rt < 2; ++rt) {
        int row = rt * 16 + l15;
        #pragma unroll
        for (int kc = 0; kc < 2; ++kc)
            koff[rt][kc] = row * 64 + 8 * ((4 * kc + g) ^ (row & 7));
    }
    #pragma unroll
    for (int dt = 0; dt < 4; ++dt) {
        int drow = dt * 16 + l15;
        voff[dt][0] = 4096 + drow * 32 + 8 * (((g >> 1)    ) ^ ((drow >> 1) & 3)) + 4 * (g & 1);
        voff[dt][1] = 4096 + drow * 32 + 8 * ((2 + (g >> 1)) ^ ((drow >> 1) & 3)) + 4 * (g & 1);
    }

    float m = -INFINITY, lsum = 0.f;
    f32x4 acc[4];
    #pragma unroll
    for (int dt = 0; dt < 4; ++dt) acc[dt] = (f32x4){0.f, 0.f, 0.f, 0.f};

    const int NIT = 64;   // 2048 keys / 32
    int buf = 0;
    for (int it = 0; it < NIT; ++it) {
        int4 na, nc, nv;
        const bool pf = (it + 1 < NIT);
        if (pf) { // T14: issue next-tile loads early; latency hides under compute
            na = *(const int4*)(gkh + (it + 1) * 2048);
            nc = *(const int4*)(gkl + (it + 1) * 2048);
            nv = *(const int4*)(gv + (it + 1) * 32);
        }
        const unsigned short* L = GL + buf * 6144;

        // QK^T (swapped): c[rt] holds S'[key = 16rt+4g+r][q = l15], log2 units
        f32x4 c[2];
        __builtin_amdgcn_s_setprio(1);
        #pragma unroll
        for (int rt = 0; rt < 2; ++rt) {
            bf16x8 a0 = *(const bf16x8*)&L[koff[rt][0]];
            bf16x8 a1 = *(const bf16x8*)&L[koff[rt][1]];
            bf16x8 b0 = *(const bf16x8*)&L[2048 + koff[rt][0]];
            bf16x8 b1 = *(const bf16x8*)&L[2048 + koff[rt][1]];
            f32x4 cc = (f32x4){0.f, 0.f, 0.f, 0.f};
            cc = __builtin_amdgcn_mfma_f32_16x16x32_bf16(a0, qh[0], cc, 0, 0, 0);
            cc = __builtin_amdgcn_mfma_f32_16x16x32_bf16(a1, qh[1], cc, 0, 0, 0);
            cc = __builtin_amdgcn_mfma_f32_16x16x32_bf16(a0, ql[0], cc, 0, 0, 0);
            cc = __builtin_amdgcn_mfma_f32_16x16x32_bf16(a1, ql[1], cc, 0, 0, 0);
            cc = __builtin_amdgcn_mfma_f32_16x16x32_bf16(b0, qh[0], cc, 0, 0, 0);
            cc = __builtin_amdgcn_mfma_f32_16x16x32_bf16(b1, qh[1], cc, 0, 0, 0);
            c[rt] = cc;
        }
        __builtin_amdgcn_s_setprio(0);

        float s[8];
        #pragma unroll
        for (int r = 0; r < 4; ++r) { s[r] = c[0][r]; s[4 + r] = c[1][r]; }
        float pmax = fmaxf(fmaxf(fmaxf(s[0], s[1]), fmaxf(s[2], s[3])),
                           fmaxf(fmaxf(s[4], s[5]), fmaxf(s[6], s[7])));
        if (!__all(pmax <= m + 11.5f)) {     // T13 defer-max, THR = 8 nats (log2 units)
            float tmax = pmax;
            #pragma unroll
            for (int off = 1; off < 64; off <<= 1) tmax = fmaxf(tmax, __shfl_xor(tmax, off, 64));
            if (tmax > m) {
                float fac = exp2f(m - tmax);
                m = tmax; lsum *= fac;
                #pragma unroll
                for (int dt = 0; dt < 4; ++dt) {
                    acc[dt][0] *= fac; acc[dt][1] *= fac; acc[dt][2] *= fac; acc[dt][3] *= fac;
                }
            }
        }
        float p[8];
        float psum = 0.f;
        #pragma unroll
        for (int q = 0; q < 8; ++q) {
            p[q] = exp2f(s[q] - m);
            psum += p[q];
        }
        lsum += psum;
        union { unsigned int u[4]; bf16x8 v8; } pk;
        asm("v_cvt_pk_bf16_f32 %0, %1, %2" : "=v"(pk.u[0]) : "v"(p[0]), "v"(p[1]));
        asm("v_cvt_pk_bf16_f32 %0, %1, %2" : "=v"(pk.u[1]) : "v"(p[2]), "v"(p[3]));
        asm("v_cvt_pk_bf16_f32 %0, %1, %2" : "=v"(pk.u[2]) : "v"(p[4]), "v"(p[5]));
        asm("v_cvt_pk_bf16_f32 %0, %1, %2" : "=v"(pk.u[3]) : "v"(p[6]), "v"(p[7]));
        bf16x8 pa = pk.v8;

        __builtin_amdgcn_s_setprio(1);
        #pragma unroll
        for (int dt = 0; dt < 4; ++dt) {
            bf16x4 va = *(const bf16x4*)&L[voff[dt][0]];
            bf16x4 vb = *(const bf16x4*)&L[voff[dt][1]];
            bf16x8 vf = {va[0], va[1], va[2], va[3], vb[0], vb[1], vb[2], vb[3]};
            acc[dt] = __builtin_amdgcn_mfma_f32_16x16x32_bf16(pa, vf, acc[dt], 0, 0, 0);
        }
        __builtin_amdgcn_s_setprio(0);

        if (pf) { // write prefetched tile into other buffer
            unsigned short* D = GL + (buf ^ 1) * 6144;
            *(int4*)&D[kdst] = na;
            *(int4*)&D[2048 + kdst] = nc;
            *(int4*)&D[vdst] = nv;
        }
        __syncthreads();
        buf ^= 1;
    }

    // per-wave reduce lsum (m already wave-uniform)
    #pragma unroll
    for (int off = 1; off < 64; off <<= 1) lsum += __shfl_xor(lsum, off, 64);

    // group merge via LDS: grp1 publishes, grp0 merges (lane-symmetric slots)
    float* mrg = (float*)lds;
    const int mbase = wv * 1026;
    if (grp == 1) {
        #pragma unroll
        for (int dt = 0; dt < 4; ++dt)
            #pragma unroll
            for (int r = 0; r < 4; ++r)
                mrg[mbase + (dt * 4 + r) * 64 + lane] = acc[dt][r];
        if (lane == 0) { mrg[mbase + 1024] = m; mrg[mbase + 1025] = lsum; }
    }
    __syncthreads();
    if (grp == 0) {
        float mB = mrg[mbase + 1024];
        float lB = mrg[mbase + 1025];
        float M = fmaxf(m, mB);
        float fA = exp2f(m - M), fB = exp2f(mB - M);
        float lOut = lsum * fA + lB * fB;
        const int unit = ((b * 64 + qblk) * 4 + ks) * 4 + wv;
        if (lane == 0) { mlw[2 * unit] = M; mlw[2 * unit + 1] = lOut; }
        float* ab = accw + unit * 1024;
        #pragma unroll
        for (int dt = 0; dt < 4; ++dt)
            #pragma unroll
            for (int r = 0; r < 4; ++r) {
                float v = acc[dt][r] * fA + mrg[mbase + (dt * 4 + r) * 64 + lane] * fB;
                ab[(4 * g + r) * 64 + dt * 16 + l15] = v;
            }
    }
}

// ---------------------------------------------------------------------------
// finalize: per batch M = max m_u, L = sum l_u 2^{m_u-M}; out = sum_ks acc*2^{m-M}/L
// grid 128 = (b, qblk). out layout [B][4096][64] == reference reshape (flat no-op).
// ---------------------------------------------------------------------------
__global__ __launch_bounds__(256) void finalize_kernel(
    const float* __restrict__ accw, const float* __restrict__ mlw, float* __restrict__ out)
{
    const int b = blockIdx.x >> 6;
    const int qblk = blockIdx.x & 63;
    const int tid = threadIdx.x;
    __shared__ float red[256];
    const float* mlb = mlw + b * 2048;

    float mloc = -INFINITY;
    for (int u = tid; u < 1024; u += 256) mloc = fmaxf(mloc, mlb[2 * u]);
    red[tid] = mloc; __syncthreads();
    for (int s = 128; s > 0; s >>= 1) {
        if (tid < s) red[tid] = fmaxf(red[tid], red[tid + s]);
        __syncthreads();
    }
    const float Mb = red[0];
    __syncthreads();
    float lloc = 0.f;
    for (int u = tid; u < 1024; u += 256) lloc += mlb[2 * u + 1] * exp2f(mlb[2 * u] - Mb);
    red[tid] = lloc; __syncthreads();
    for (int s = 128; s > 0; s >>= 1) {
        if (tid < s) red[tid] += red[tid + s];
        __syncthreads();
    }
    const float invL = 1.0f / red[0];

    const int d = tid & 63, wgrp = tid >> 6;
    float scl[4];
    int units[4];
    #pragma unroll
    for (int ks = 0; ks < 4; ++ks) {
        units[ks] = ((b * 64 + qblk) * 4 + ks) * 4 + wgrp;
        scl[ks] = exp2f(mlw[2 * units[ks]] - Mb) * invL;
    }
    #pragma unroll
    for (int rr = 0; rr < 16; ++rr) {
        float o = 0.f;
        #pragma unroll
        for (int ks = 0; ks < 4; ++ks)
            o = fmaf(accw[units[ks] * 1024 + rr * 64 + d], scl[ks], o);
        out[(b * 4096 + qblk * 64 + wgrp * 16 + rr) * 64 + d] = o;
    }
}

// ---------------------------------------------------------------------------
extern "C" void kernel_launch(void* const* d_in, const int* in_sizes, int n_in,
                              void* d_out, int out_size, void* d_ws, size_t ws_size,
                              hipStream_t stream) {
    const float* zx   = (const float*)d_in[0];
    const float* zy   = (const float*)d_in[1];
    const float* q_w  = (const float*)d_in[2];
    const float* q_b  = (const float*)d_in[3];
    const float* px_w = (const float*)d_in[4];
    const float* px_b = (const float*)d_in[5];
    const float* k_w  = (const float*)d_in[6];
    const float* k_b  = (const float*)d_in[7];
    const float* py_w = (const float*)d_in[8];
    const float* py_b = (const float*)d_in[9];
    const float* v_w  = (const float*)d_in[10];
    const float* v_b  = (const float*)d_in[11];

    unsigned short* qhi = (unsigned short*)d_ws;          // [2][4096][64]
    unsigned short* qlo = qhi + 524288;                   // [2][4096][64]
    unsigned short* khi = qlo + 524288;                   // [2][16384][64]
    unsigned short* klo = khi + 2097152;                  // [2][16384][64]
    unsigned short* vt  = klo + 2097152;                  // [2][64][16384] (transposed)
    float* accw = (float*)(vt + 2097152);                 // [2048 units][16][64]
    float* mlw  = accw + 2097152;                         // [2048 units][2]
    float* out  = (float*)d_out;

    proj_q_kernel<<<128, 256, 0, stream>>>(zx, q_w, q_b, px_w, px_b, qhi, qlo);
    proj_kv_kernel<<<512, 256, 0, stream>>>(zy, k_w, k_b, py_w, py_b, v_w, v_b, khi, klo, vt);
    attn_kernel<<<512, 512, 0, stream>>>(qhi, qlo, khi, klo, vt, accw, mlw);
    finalize_kernel<<<128, 256, 0, stream>>>(accw, mlw, out);
}

// Round 9
// 131.107 us; speedup vs baseline: 1.4953x; 1.0709x over previous
//
#include <hip/hip_runtime.h>
#include <hip/hip_bf16.h>
#include <stdint.h>

typedef short bf16x8 __attribute__((ext_vector_type(8)));
typedef short bf16x4 __attribute__((ext_vector_type(4)));
typedef float f32x4  __attribute__((ext_vector_type(4)));

__device__ __forceinline__ unsigned short f2bf(float x) {
    unsigned int u = __float_as_uint(x);
    unsigned int r = (u + 0x7fffu + ((u >> 16) & 1u)) >> 16;
    return (unsigned short)r;
}
__device__ __forceinline__ float bf2f(unsigned short h) {
    return __uint_as_float(((unsigned int)h) << 16);
}
__device__ __forceinline__ float4 fma4(float4 z, float s, float4 a) {
    a.x = fmaf(z.x, s, a.x); a.y = fmaf(z.y, s, a.y);
    a.z = fmaf(z.z, s, a.z); a.w = fmaf(z.w, s, a.w);
    return a;
}
// raw 2^x (no OCML range-fixup; inputs here are <= 0 and finite-or--inf, safe)
__device__ __forceinline__ float exp2_raw(float x) {
    float r;
    asm("v_exp_f32 %0, %1" : "=v"(r) : "v"(x));
    return r;
}

// q pre-scale: (1/sqrt(64)) * log2(e)  -> scores come out in log2 units
#define QSCALE 0.18033688f

// ---------------------------------------------------------------------------
// proj_q: q[b, i*64+j, d] = (zx@qw + qb + PE·pxw + pxb) * 0.125*log2e
// PE collapses: sin(4i)*A[d] + cos(4i)*B[d] + sin(4j)*C[d] + cos(4j)*E[d] + F[d]
// grid 128 = (b, i). Output: split bf16 (hi, lo), pre-scaled.
// ---------------------------------------------------------------------------
__global__ __launch_bounds__(256) void proj_q_kernel(
    const float* __restrict__ zx, const float* __restrict__ qw, const float* __restrict__ qb,
    const float* __restrict__ pxw, const float* __restrict__ pxb,
    unsigned short* __restrict__ qhi, unsigned short* __restrict__ qlo)
{
    const int b = blockIdx.x >> 6;
    const int i = blockIdx.x & 63;
    const int tid = threadIdx.x;
    __shared__ __align__(16) float zt[64][68];
    __shared__ __align__(16) float wt[64][68];
    __shared__ float Af[64], Bf[64], Cf[64], Ef[64], Ff[64], sw[64], cw[64];

    {
        const int w = tid & 63, c0 = tid >> 6;
        #pragma unroll
        for (int cc = 0; cc < 16; ++cc) {
            int c = cc * 4 + c0;
            zt[c][w] = zx[((b * 64 + c) * 64 + i) * 64 + w];
        }
        #pragma unroll
        for (int ii = 0; ii < 16; ++ii) {
            int idx = tid + 256 * ii;
            wt[idx >> 6][idx & 63] = qw[idx];
        }
    }
    if (tid < 64) {
        int d = tid;
        float A = 0.f;
        for (int c = 0; c < 16; ++c) A += pxw[c * 64 + d];
        float F = 0.f;
        for (int c = 19; c < 64; ++c) F += pxw[c * 64 + d];
        Af[d] = A; Bf[d] = pxw[16 * 64 + d]; Cf[d] = pxw[17 * 64 + d]; Ef[d] = pxw[18 * 64 + d];
        Ff[d] = F + pxb[d] + qb[d];
        sw[d] = sinf(4.0f * (float)d); cw[d] = cosf(4.0f * (float)d);
    }
    __syncthreads();

    const int d = tid & 63, wb = (tid >> 6) * 16;
    float4 a0 = {0,0,0,0}, a1 = {0,0,0,0}, a2 = {0,0,0,0}, a3 = {0,0,0,0};
    for (int c = 0; c < 64; ++c) {
        float wvv = wt[c][d];
        const float4* zp = (const float4*)&zt[c][wb];
        a0 = fma4(zp[0], wvv, a0); a1 = fma4(zp[1], wvv, a1);
        a2 = fma4(zp[2], wvv, a2); a3 = fma4(zp[3], wvv, a3);
    }
    float acc[16] = {a0.x,a0.y,a0.z,a0.w, a1.x,a1.y,a1.z,a1.w,
                     a2.x,a2.y,a2.z,a2.w, a3.x,a3.y,a3.z,a3.w};
    float pe0 = sw[i] * Af[d] + cw[i] * Bf[d] + Ff[d];
    #pragma unroll
    for (int jj = 0; jj < 16; ++jj) {
        int j = wb + jj;
        float val = (acc[jj] + pe0 + sw[j] * Cf[d] + cw[j] * Ef[d]) * QSCALE;
        int idx = (b * 4096 + i * 64 + j) * 64 + d;
        unsigned short hi = f2bf(val);
        qhi[idx] = hi;
        qlo[idx] = f2bf(val - bf2f(hi));
    }
}

// ---------------------------------------------------------------------------
// proj_kv: k = zy@kw + kb + PE·pyw + pyb  (split bf16, [B][16384][64])
//          v = zy@vw + vb                 (bf16, TRANSPOSED [B][64][16384])
// grid 512 = (b, kimg, h).
// ---------------------------------------------------------------------------
__global__ __launch_bounds__(256) void proj_kv_kernel(
    const float* __restrict__ zy,
    const float* __restrict__ kw, const float* __restrict__ kb_,
    const float* __restrict__ pyw, const float* __restrict__ pyb,
    const float* __restrict__ vw, const float* __restrict__ vb_,
    unsigned short* __restrict__ khi, unsigned short* __restrict__ klo,
    unsigned short* __restrict__ vt)
{
    const int bk = blockIdx.x >> 6;     // 0..7
    const int b = bk >> 2, kimg = bk & 3;
    const int h = blockIdx.x & 63;
    const int tid = threadIdx.x;
    __shared__ __align__(16) float zt[64][68];
    __shared__ __align__(16) float kwt[64][68];
    __shared__ __align__(16) float vwt[64][68];
    __shared__ float A2[64], B2[64], C2[64], E2[64], F2[64], vb[64], sw[64], cw[64];

    {
        const int w = tid & 63, c0 = tid >> 6;
        #pragma unroll
        for (int cc = 0; cc < 16; ++cc) {
            int c = cc * 4 + c0;
            zt[c][w] = zy[(((b * 4 + kimg) * 64 + c) * 64 + h) * 64 + w];
        }
        #pragma unroll
        for (int ii = 0; ii < 16; ++ii) {
            int idx = tid + 256 * ii;
            kwt[idx >> 6][idx & 63] = kw[idx];
            vwt[idx >> 6][idx & 63] = vw[idx];
        }
    }
    if (tid < 64) {
        int d = tid;
        float A = 0.f;
        for (int c = 0; c < 16; ++c) A += pyw[c * 64 + d];
        float F = 0.f;
        for (int c = 19; c < 64; ++c) F += pyw[c * 64 + d];
        A2[d] = A; B2[d] = pyw[16 * 64 + d]; C2[d] = pyw[17 * 64 + d]; E2[d] = pyw[18 * 64 + d];
        F2[d] = F + pyb[d] + kb_[d];
        vb[d] = vb_[d];
        sw[d] = sinf(4.0f * (float)d); cw[d] = cosf(4.0f * (float)d);
    }
    __syncthreads();

    const int d = tid & 63, wb = (tid >> 6) * 16;
    float4 ka0 = {0,0,0,0}, ka1 = {0,0,0,0}, ka2 = {0,0,0,0}, ka3 = {0,0,0,0};
    float4 va0 = {0,0,0,0}, va1 = {0,0,0,0}, va2 = {0,0,0,0}, va3 = {0,0,0,0};
    for (int c = 0; c < 64; ++c) {
        float wk = kwt[c][d], wvv = vwt[c][d];
        const float4* zp = (const float4*)&zt[c][wb];
        float4 z0 = zp[0], z1 = zp[1], z2 = zp[2], z3 = zp[3];
        ka0 = fma4(z0, wk, ka0); ka1 = fma4(z1, wk, ka1);
        ka2 = fma4(z2, wk, ka2); ka3 = fma4(z3, wk, ka3);
        va0 = fma4(z0, wvv, va0); va1 = fma4(z1, wvv, va1);
        va2 = fma4(z2, wvv, va2); va3 = fma4(z3, wvv, va3);
    }
    float kacc[16] = {ka0.x,ka0.y,ka0.z,ka0.w, ka1.x,ka1.y,ka1.z,ka1.w,
                      ka2.x,ka2.y,ka2.z,ka2.w, ka3.x,ka3.y,ka3.z,ka3.w};
    float vacc[16] = {va0.x,va0.y,va0.z,va0.w, va1.x,va1.y,va1.z,va1.w,
                      va2.x,va2.y,va2.z,va2.w, va3.x,va3.y,va3.z,va3.w};
    __syncthreads();   // all zt reads done; reuse zt region as vtmp

    float (*vtmp)[65] = (float(*)[65])&zt[0][0];
    const int key0 = kimg * 4096 + h * 64;
    float pe0 = sw[h] * A2[d] + cw[h] * B2[d] + F2[d];
    #pragma unroll
    for (int jj = 0; jj < 16; ++jj) {
        int j = wb + jj;
        float kv = kacc[jj] + pe0 + sw[j] * C2[d] + cw[j] * E2[d];
        int idx = (b * 16384 + key0 + j) * 64 + d;
        unsigned short hi = f2bf(kv);
        khi[idx] = hi;
        klo[idx] = f2bf(kv - bf2f(hi));
        vtmp[d][j] = vacc[jj] + vb[d];
    }
    __syncthreads();
    // packed transposed v store: thread -> (drow = tid>>2, 16 keys)
    {
        const int drow = tid >> 2, wc0 = (tid & 3) * 16;
        #pragma unroll
        for (int jj = 0; jj < 16; jj += 2) {
            unsigned int u = (unsigned int)f2bf(vtmp[drow][wc0 + jj]) |
                             ((unsigned int)f2bf(vtmp[drow][wc0 + jj + 1]) << 16);
            *(unsigned int*)&vt[(b * 64 + drow) * 16384 + key0 + wc0 + jj] = u;
        }
    }
}

// ---------------------------------------------------------------------------
// attn: grid 512 blocks x 512 threads (8 waves = 2 groups of 4).
// bid&7 -> (b,ks) slice (XCD L2-resident); bid>>3 -> qblk (64 q-rows).
// Group grp handles keys [ks*4096 + grp*2048, +2048); groups merge via LDS.
// Per grp-buf region (6656 ush): khi 2048 | klo 2048 | V padded 64 rows x 40
// (32 keys + 8 pad -> conflict-free b64 reads / b128 writes, no swizzle).
// Softmax via raw v_exp_f32 in log2 domain (q pre-scaled by log2e/8).
// ---------------------------------------------------------------------------
__global__ __launch_bounds__(512, 4) void attn_kernel(
    const unsigned short* __restrict__ qhi, const unsigned short* __restrict__ qlo,
    const unsigned short* __restrict__ khi, const unsigned short* __restrict__ klo,
    const unsigned short* __restrict__ vt,
    float* __restrict__ accw, float* __restrict__ mlw)
{
    __shared__ __align__(16) unsigned short lds[26624]; // 52KB: [grp2][buf2][k 4096 | v 2560]
    const int tid = threadIdx.x;
    const int tid8 = tid & 255;
    const int grp = tid >> 8;               // key-half group
    const int xcd = blockIdx.x & 7;
    const int qblk = blockIdx.x >> 3;       // 0..63
    const int b = xcd >> 2, ks = xcd & 3;
    const int lane = tid & 63, wv = (tid >> 6) & 3;
    const int l15 = lane & 15, g = lane >> 4;

    // q fragments (registers, whole kernel); q is pre-scaled by log2e/8
    bf16x8 qh[2], ql[2];
    {
        int qr = (b * 4096 + qblk * 64 + wv * 16 + l15) * 64;
        qh[0] = *(const bf16x8*)&qhi[qr + 8 * g];
        qh[1] = *(const bf16x8*)&qhi[qr + 32 + 8 * g];
        ql[0] = *(const bf16x8*)&qlo[qr + 8 * g];
        ql[1] = *(const bf16x8*)&qlo[qr + 32 + 8 * g];
    }

    unsigned short* GL = lds + grp * 13312;
    // staging: thread stages one 16B chunk per tile-component.
    // K: XOR-swizzled slots (proven). V: padded rows, linear (conflict-free).
    const int trow = tid8 >> 3, tc = tid8 & 7;
    const int kdst = trow * 64 + 8 * (tc ^ (trow & 7));
    const int vd = tid8 >> 2, vs = tid8 & 3;
    const int vdst = 4096 + vd * 40 + vs * 8;
    const int keybase = ks * 4096 + grp * 2048;
    const unsigned short* gkh = khi + (b * 16384 + keybase + trow) * 64 + 8 * tc;
    const unsigned short* gkl = klo + (b * 16384 + keybase + trow) * 64 + 8 * tc;
    const unsigned short* gv  = vt  + (b * 64 + vd) * 16384 + keybase + 8 * vs;

    { // prologue: stage tile 0 into buffer 0
        int4 a = *(const int4*)gkh;
        int4 c = *(const int4*)gkl;
        int4 v = *(const int4*)gv;
        *(int4*)&GL[kdst] = a;
        *(int4*)&GL[2048 + kdst] = c;
        *(int4*)&GL[vdst] = v;
    }
    __syncthreads();

    // fragment LDS read offsets
    int koff[2][2], voff[4][2];
    #pragma unroll
    for (int rt = 0; rt < 2; ++rt) {
        int row = rt * 16 + l15;
        #pragma unroll
        for (int kc = 0; kc < 2; ++kc)
            koff[rt][kc] = row * 64 + 8 * ((4 * kc + g) ^ (row & 7));
    }
    #pragma unroll
    for (int dt = 0; dt < 4; ++dt) {
        int drow = dt * 16 + l15;
        voff[dt][0] = 4096 + drow * 40 + 4 * g;        // keys 4g..4g+3
        voff[dt][1] = 4096 + drow * 40 + 16 + 4 * g;   // keys 16+4g..+3
    }

    float m = -INFINITY, lsum = 0.f;
    f32x4 acc[4];
    #pragma unroll
    for (int dt = 0; dt < 4; ++dt) acc[dt] = (f32x4){0.f, 0.f, 0.f, 0.f};

    const int NIT = 64;   // 2048 keys / 32
    int buf = 0;
    for (int it = 0; it < NIT; ++it) {
        int4 na, nc, nv;
        const bool pf = (it + 1 < NIT);
        if (pf) { // T14: issue next-tile loads early; latency hides under compute
            na = *(const int4*)(gkh + (it + 1) * 2048);
            nc = *(const int4*)(gkl + (it + 1) * 2048);
            nv = *(const int4*)(gv + (it + 1) * 32);
        }
        const unsigned short* L = GL + buf * 6656;

        // QK^T (swapped): c[rt] holds S'[key = 16rt+4g+r][q = l15], log2 units
        f32x4 c[2];
        __builtin_amdgcn_s_setprio(1);
        #pragma unroll
        for (int rt = 0; rt < 2; ++rt) {
            bf16x8 a0 = *(const bf16x8*)&L[koff[rt][0]];
            bf16x8 a1 = *(const bf16x8*)&L[koff[rt][1]];
            bf16x8 b0 = *(const bf16x8*)&L[2048 + koff[rt][0]];
            bf16x8 b1 = *(const bf16x8*)&L[2048 + koff[rt][1]];
            f32x4 cc = (f32x4){0.f, 0.f, 0.f, 0.f};
            cc = __builtin_amdgcn_mfma_f32_16x16x32_bf16(a0, qh[0], cc, 0, 0, 0);
            cc = __builtin_amdgcn_mfma_f32_16x16x32_bf16(a1, qh[1], cc, 0, 0, 0);
            cc = __builtin_amdgcn_mfma_f32_16x16x32_bf16(a0, ql[0], cc, 0, 0, 0);
            cc = __builtin_amdgcn_mfma_f32_16x16x32_bf16(a1, ql[1], cc, 0, 0, 0);
            cc = __builtin_amdgcn_mfma_f32_16x16x32_bf16(b0, qh[0], cc, 0, 0, 0);
            cc = __builtin_amdgcn_mfma_f32_16x16x32_bf16(b1, qh[1], cc, 0, 0, 0);
            c[rt] = cc;
        }
        __builtin_amdgcn_s_setprio(0);

        float s[8];
        #pragma unroll
        for (int r = 0; r < 4; ++r) { s[r] = c[0][r]; s[4 + r] = c[1][r]; }
        float pmax = fmaxf(fmaxf(fmaxf(s[0], s[1]), fmaxf(s[2], s[3])),
                           fmaxf(fmaxf(s[4], s[5]), fmaxf(s[6], s[7])));
        if (!__all(pmax <= m + 11.5f)) {     // T13 defer-max, THR = 8 nats (log2 units)
            float tmax = pmax;
            #pragma unroll
            for (int off = 1; off < 64; off <<= 1) tmax = fmaxf(tmax, __shfl_xor(tmax, off, 64));
            if (tmax > m) {
                float fac = exp2_raw(m - tmax);
                m = tmax; lsum *= fac;
                #pragma unroll
                for (int dt = 0; dt < 4; ++dt) {
                    acc[dt][0] *= fac; acc[dt][1] *= fac; acc[dt][2] *= fac; acc[dt][3] *= fac;
                }
            }
        }
        float p[8];
        float psum = 0.f;
        #pragma unroll
        for (int q = 0; q < 8; ++q) {
            p[q] = exp2_raw(s[q] - m);
            psum += p[q];
        }
        lsum += psum;
        union { unsigned int u[4]; bf16x8 v8; } pk;
        asm("v_cvt_pk_bf16_f32 %0, %1, %2" : "=v"(pk.u[0]) : "v"(p[0]), "v"(p[1]));
        asm("v_cvt_pk_bf16_f32 %0, %1, %2" : "=v"(pk.u[1]) : "v"(p[2]), "v"(p[3]));
        asm("v_cvt_pk_bf16_f32 %0, %1, %2" : "=v"(pk.u[2]) : "v"(p[4]), "v"(p[5]));
        asm("v_cvt_pk_bf16_f32 %0, %1, %2" : "=v"(pk.u[3]) : "v"(p[6]), "v"(p[7]));
        bf16x8 pa = pk.v8;

        __builtin_amdgcn_s_setprio(1);
        #pragma unroll
        for (int dt = 0; dt < 4; ++dt) {
            bf16x4 va = *(const bf16x4*)&L[voff[dt][0]];
            bf16x4 vb = *(const bf16x4*)&L[voff[dt][1]];
            bf16x8 vf = {va[0], va[1], va[2], va[3], vb[0], vb[1], vb[2], vb[3]};
            acc[dt] = __builtin_amdgcn_mfma_f32_16x16x32_bf16(pa, vf, acc[dt], 0, 0, 0);
        }
        __builtin_amdgcn_s_setprio(0);

        if (pf) { // write prefetched tile into other buffer
            unsigned short* D = GL + (buf ^ 1) * 6656;
            *(int4*)&D[kdst] = na;
            *(int4*)&D[2048 + kdst] = nc;
            *(int4*)&D[vdst] = nv;
        }
        __syncthreads();
        buf ^= 1;
    }

    // per-wave reduce lsum (m already wave-uniform)
    #pragma unroll
    for (int off = 1; off < 64; off <<= 1) lsum += __shfl_xor(lsum, off, 64);

    // group merge via LDS: grp1 publishes, grp0 merges (lane-symmetric slots)
    float* mrg = (float*)lds;
    const int mbase = wv * 1026;
    if (grp == 1) {
        #pragma unroll
        for (int dt = 0; dt < 4; ++dt)
            #pragma unroll
            for (int r = 0; r < 4; ++r)
                mrg[mbase + (dt * 4 + r) * 64 + lane] = acc[dt][r];
        if (lane == 0) { mrg[mbase + 1024] = m; mrg[mbase + 1025] = lsum; }
    }
    __syncthreads();
    if (grp == 0) {
        float mB = mrg[mbase + 1024];
        float lB = mrg[mbase + 1025];
        float M = fmaxf(m, mB);
        float fA = exp2_raw(m - M), fB = exp2_raw(mB - M);
        float lOut = lsum * fA + lB * fB;
        const int unit = ((b * 64 + qblk) * 4 + ks) * 4 + wv;
        if (lane == 0) { mlw[2 * unit] = M; mlw[2 * unit + 1] = lOut; }
        float* ab = accw + unit * 1024;
        #pragma unroll
        for (int dt = 0; dt < 4; ++dt)
            #pragma unroll
            for (int r = 0; r < 4; ++r) {
                float v = acc[dt][r] * fA + mrg[mbase + (dt * 4 + r) * 64 + lane] * fB;
                ab[(4 * g + r) * 64 + dt * 16 + l15] = v;
            }
    }
}

// ---------------------------------------------------------------------------
// finalize: per batch M = max m_u, L = sum l_u 2^{m_u-M}; out = sum_ks acc*2^{m-M}/L
// grid 128 = (b, qblk). out layout [B][4096][64] == reference reshape (flat no-op).
// ---------------------------------------------------------------------------
__global__ __launch_bounds__(256) void finalize_kernel(
    const float* __restrict__ accw, const float* __restrict__ mlw, float* __restrict__ out)
{
    const int b = blockIdx.x >> 6;
    const int qblk = blockIdx.x & 63;
    const int tid = threadIdx.x;
    __shared__ float red[256];
    const float* mlb = mlw + b * 2048;

    float mloc = -INFINITY;
    for (int u = tid; u < 1024; u += 256) mloc = fmaxf(mloc, mlb[2 * u]);
    red[tid] = mloc; __syncthreads();
    for (int s = 128; s > 0; s >>= 1) {
        if (tid < s) red[tid] = fmaxf(red[tid], red[tid + s]);
        __syncthreads();
    }
    const float Mb = red[0];
    __syncthreads();
    float lloc = 0.f;
    for (int u = tid; u < 1024; u += 256) lloc += mlb[2 * u + 1] * exp2f(mlb[2 * u] - Mb);
    red[tid] = lloc; __syncthreads();
    for (int s = 128; s > 0; s >>= 1) {
        if (tid < s) red[tid] += red[tid + s];
        __syncthreads();
    }
    const float invL = 1.0f / red[0];

    const int d = tid & 63, wgrp = tid >> 6;
    float scl[4];
    int units[4];
    #pragma unroll
    for (int ks = 0; ks < 4; ++ks) {
        units[ks] = ((b * 64 + qblk) * 4 + ks) * 4 + wgrp;
        scl[ks] = exp2f(mlw[2 * units[ks]] - Mb) * invL;
    }
    #pragma unroll
    for (int rr = 0; rr < 16; ++rr) {
        float o = 0.f;
        #pragma unroll
        for (int ks = 0; ks < 4; ++ks)
            o = fmaf(accw[units[ks] * 1024 + rr * 64 + d], scl[ks], o);
        out[(b * 4096 + qblk * 64 + wgrp * 16 + rr) * 64 + d] = o;
    }
}

// ---------------------------------------------------------------------------
extern "C" void kernel_launch(void* const* d_in, const int* in_sizes, int n_in,
                              void* d_out, int out_size, void* d_ws, size_t ws_size,
                              hipStream_t stream) {
    const float* zx   = (const float*)d_in[0];
    const float* zy   = (const float*)d_in[1];
    const float* q_w  = (const float*)d_in[2];
    const float* q_b  = (const float*)d_in[3];
    const float* px_w = (const float*)d_in[4];
    const float* px_b = (const float*)d_in[5];
    const float* k_w  = (const float*)d_in[6];
    const float* k_b  = (const float*)d_in[7];
    const float* py_w = (const float*)d_in[8];
    const float* py_b = (const float*)d_in[9];
    const float* v_w  = (const float*)d_in[10];
    const float* v_b  = (const float*)d_in[11];

    unsigned short* qhi = (unsigned short*)d_ws;          // [2][4096][64]
    unsigned short* qlo = qhi + 524288;                   // [2][4096][64]
    unsigned short* khi = qlo + 524288;                   // [2][16384][64]
    unsigned short* klo = khi + 2097152;                  // [2][16384][64]
    unsigned short* vt  = klo + 2097152;                  // [2][64][16384] (transposed)
    float* accw = (float*)(vt + 2097152);                 // [2048 units][16][64]
    float* mlw  = accw + 2097152;                         // [2048 units][2]
    float* out  = (float*)d_out;

    proj_q_kernel<<<128, 256, 0, stream>>>(zx, q_w, q_b, px_w, px_b, qhi, qlo);
    proj_kv_kernel<<<512, 256, 0, stream>>>(zy, k_w, k_b, py_w, py_b, v_w, v_b, khi, klo, vt);
    attn_kernel<<<512, 512, 0, stream>>>(qhi, qlo, khi, klo, vt, accw, mlw);
    finalize_kernel<<<128, 256, 0, stream>>>(accw, mlw, out);
}

// Round 11
// 130.204 us; speedup vs baseline: 1.5057x; 1.0069x over previous
//
#include <hip/hip_runtime.h>
#include <hip/hip_bf16.h>
#include <stdint.h>

typedef short bf16x8 __attribute__((ext_vector_type(8)));
typedef short bf16x4 __attribute__((ext_vector_type(4)));
typedef float f32x4  __attribute__((ext_vector_type(4)));

__device__ __forceinline__ unsigned short f2bf(float x) {
    unsigned int u = __float_as_uint(x);
    unsigned int r = (u + 0x7fffu + ((u >> 16) & 1u)) >> 16;
    return (unsigned short)r;
}
__device__ __forceinline__ float bf2f(unsigned short h) {
    return __uint_as_float(((unsigned int)h) << 16);
}
__device__ __forceinline__ float4 fma4(float4 z, float s, float4 a) {
    a.x = fmaf(z.x, s, a.x); a.y = fmaf(z.y, s, a.y);
    a.z = fmaf(z.z, s, a.z); a.w = fmaf(z.w, s, a.w);
    return a;
}
// raw 2^x (no OCML range-fixup; args <= 0 or bounded, safe)
__device__ __forceinline__ float exp2_raw(float x) {
    float r;
    asm("v_exp_f32 %0, %1" : "=v"(r) : "v"(x));
    return r;
}

// q pre-scale: (1/sqrt(64)) * log2(e)  -> scores come out in log2 units
#define QSCALE 0.18033688f

// ---------------------------------------------------------------------------
// proj_q: q[b, i*64+j, d] = (zx@qw + qb + PE·pxw + pxb) * 0.125*log2e
// PE collapses: sin(4i)*A[d] + cos(4i)*B[d] + sin(4j)*C[d] + cos(4j)*E[d] + F[d]
// grid 128 = (b, i). Output: split bf16 (hi, lo), pre-scaled.
// ---------------------------------------------------------------------------
__global__ __launch_bounds__(256) void proj_q_kernel(
    const float* __restrict__ zx, const float* __restrict__ qw, const float* __restrict__ qb,
    const float* __restrict__ pxw, const float* __restrict__ pxb,
    unsigned short* __restrict__ qhi, unsigned short* __restrict__ qlo)
{
    const int b = blockIdx.x >> 6;
    const int i = blockIdx.x & 63;
    const int tid = threadIdx.x;
    __shared__ __align__(16) float zt[64][68];
    __shared__ __align__(16) float wt[64][68];
    __shared__ float Af[64], Bf[64], Cf[64], Ef[64], Ff[64], sw[64], cw[64];

    {
        const int w = tid & 63, c0 = tid >> 6;
        #pragma unroll
        for (int cc = 0; cc < 16; ++cc) {
            int c = cc * 4 + c0;
            zt[c][w] = zx[((b * 64 + c) * 64 + i) * 64 + w];
        }
        #pragma unroll
        for (int ii = 0; ii < 16; ++ii) {
            int idx = tid + 256 * ii;
            wt[idx >> 6][idx & 63] = qw[idx];
        }
    }
    if (tid < 64) {
        int d = tid;
        float A = 0.f;
        for (int c = 0; c < 16; ++c) A += pxw[c * 64 + d];
        float F = 0.f;
        for (int c = 19; c < 64; ++c) F += pxw[c * 64 + d];
        Af[d] = A; Bf[d] = pxw[16 * 64 + d]; Cf[d] = pxw[17 * 64 + d]; Ef[d] = pxw[18 * 64 + d];
        Ff[d] = F + pxb[d] + qb[d];
        sw[d] = sinf(4.0f * (float)d); cw[d] = cosf(4.0f * (float)d);
    }
    __syncthreads();

    const int d = tid & 63, wb = (tid >> 6) * 16;
    float4 a0 = {0,0,0,0}, a1 = {0,0,0,0}, a2 = {0,0,0,0}, a3 = {0,0,0,0};
    for (int c = 0; c < 64; ++c) {
        float wvv = wt[c][d];
        const float4* zp = (const float4*)&zt[c][wb];
        a0 = fma4(zp[0], wvv, a0); a1 = fma4(zp[1], wvv, a1);
        a2 = fma4(zp[2], wvv, a2); a3 = fma4(zp[3], wvv, a3);
    }
    float acc[16] = {a0.x,a0.y,a0.z,a0.w, a1.x,a1.y,a1.z,a1.w,
                     a2.x,a2.y,a2.z,a2.w, a3.x,a3.y,a3.z,a3.w};
    float pe0 = sw[i] * Af[d] + cw[i] * Bf[d] + Ff[d];
    #pragma unroll
    for (int jj = 0; jj < 16; ++jj) {
        int j = wb + jj;
        float val = (acc[jj] + pe0 + sw[j] * Cf[d] + cw[j] * Ef[d]) * QSCALE;
        int idx = (b * 4096 + i * 64 + j) * 64 + d;
        unsigned short hi = f2bf(val);
        qhi[idx] = hi;
        qlo[idx] = f2bf(val - bf2f(hi));
    }
}

// ---------------------------------------------------------------------------
// proj_kv: k = zy@kw + kb + PE·pyw + pyb  (split bf16, [B][16384][64])
//          v = zy@vw + vb                 (bf16, TRANSPOSED [B][64][16384])
// grid 512 = (b, kimg, h).
// ---------------------------------------------------------------------------
__global__ __launch_bounds__(256) void proj_kv_kernel(
    const float* __restrict__ zy,
    const float* __restrict__ kw, const float* __restrict__ kb_,
    const float* __restrict__ pyw, const float* __restrict__ pyb,
    const float* __restrict__ vw, const float* __restrict__ vb_,
    unsigned short* __restrict__ khi, unsigned short* __restrict__ klo,
    unsigned short* __restrict__ vt)
{
    const int bk = blockIdx.x >> 6;     // 0..7
    const int b = bk >> 2, kimg = bk & 3;
    const int h = blockIdx.x & 63;
    const int tid = threadIdx.x;
    __shared__ __align__(16) float zt[64][68];
    __shared__ __align__(16) float kwt[64][68];
    __shared__ __align__(16) float vwt[64][68];
    __shared__ float A2[64], B2[64], C2[64], E2[64], F2[64], vb[64], sw[64], cw[64];

    {
        const int w = tid & 63, c0 = tid >> 6;
        #pragma unroll
        for (int cc = 0; cc < 16; ++cc) {
            int c = cc * 4 + c0;
            zt[c][w] = zy[(((b * 4 + kimg) * 64 + c) * 64 + h) * 64 + w];
        }
        #pragma unroll
        for (int ii = 0; ii < 16; ++ii) {
            int idx = tid + 256 * ii;
            kwt[idx >> 6][idx & 63] = kw[idx];
            vwt[idx >> 6][idx & 63] = vw[idx];
        }
    }
    if (tid < 64) {
        int d = tid;
        float A = 0.f;
        for (int c = 0; c < 16; ++c) A += pyw[c * 64 + d];
        float F = 0.f;
        for (int c = 19; c < 64; ++c) F += pyw[c * 64 + d];
        A2[d] = A; B2[d] = pyw[16 * 64 + d]; C2[d] = pyw[17 * 64 + d]; E2[d] = pyw[18 * 64 + d];
        F2[d] = F + pyb[d] + kb_[d];
        vb[d] = vb_[d];
        sw[d] = sinf(4.0f * (float)d); cw[d] = cosf(4.0f * (float)d);
    }
    __syncthreads();

    const int d = tid & 63, wb = (tid >> 6) * 16;
    float4 ka0 = {0,0,0,0}, ka1 = {0,0,0,0}, ka2 = {0,0,0,0}, ka3 = {0,0,0,0};
    float4 va0 = {0,0,0,0}, va1 = {0,0,0,0}, va2 = {0,0,0,0}, va3 = {0,0,0,0};
    for (int c = 0; c < 64; ++c) {
        float wk = kwt[c][d], wvv = vwt[c][d];
        const float4* zp = (const float4*)&zt[c][wb];
        float4 z0 = zp[0], z1 = zp[1], z2 = zp[2], z3 = zp[3];
        ka0 = fma4(z0, wk, ka0); ka1 = fma4(z1, wk, ka1);
        ka2 = fma4(z2, wk, ka2); ka3 = fma4(z3, wk, ka3);
        va0 = fma4(z0, wvv, va0); va1 = fma4(z1, wvv, va1);
        va2 = fma4(z2, wvv, va2); va3 = fma4(z3, wvv, va3);
    }
    float kacc[16] = {ka0.x,ka0.y,ka0.z,ka0.w, ka1.x,ka1.y,ka1.z,ka1.w,
                      ka2.x,ka2.y,ka2.z,ka2.w, ka3.x,ka3.y,ka3.z,ka3.w};
    float vacc[16] = {va0.x,va0.y,va0.z,va0.w, va1.x,va1.y,va1.z,va1.w,
                      va2.x,va2.y,va2.z,va2.w, va3.x,va3.y,va3.z,va3.w};
    __syncthreads();   // all zt reads done; reuse zt region as vtmp

    float (*vtmp)[65] = (float(*)[65])&zt[0][0];
    const int key0 = kimg * 4096 + h * 64;
    float pe0 = sw[h] * A2[d] + cw[h] * B2[d] + F2[d];
    #pragma unroll
    for (int jj = 0; jj < 16; ++jj) {
        int j = wb + jj;
        float kv = kacc[jj] + pe0 + sw[j] * C2[d] + cw[j] * E2[d];
        int idx = (b * 16384 + key0 + j) * 64 + d;
        unsigned short hi = f2bf(kv);
        khi[idx] = hi;
        klo[idx] = f2bf(kv - bf2f(hi));
        vtmp[d][j] = vacc[jj] + vb[d];
    }
    __syncthreads();
    // packed transposed v store: thread -> (drow = tid>>2, 16 keys)
    {
        const int drow = tid >> 2, wc0 = (tid & 3) * 16;
        #pragma unroll
        for (int jj = 0; jj < 16; jj += 2) {
            unsigned int u = (unsigned int)f2bf(vtmp[drow][wc0 + jj]) |
                             ((unsigned int)f2bf(vtmp[drow][wc0 + jj + 1]) << 16);
            *(unsigned int*)&vt[(b * 64 + drow) * 16384 + key0 + wc0 + jj] = u;
        }
    }
}

// ---------------------------------------------------------------------------
// attn: grid 512 blocks x 512 threads (8 waves = 2 groups of 4).
// bid&7 -> (b,ks) slice (XCD L2-resident); bid>>3 -> qblk (64 q-rows).
// Group grp handles keys [ks*4096 + grp*2048, +2048); groups merge via LDS.
// Per grp-buf region (6144 ush): khi 2048 | klo 2048 | V 64 rows x 32 keys.
// V uses key-group XOR perm: group j (4 keys) of row r at pos j^((r>>1)&7)
// -> conflict-free b64 reads AND writes at 16-lane phase granularity.
// Max-tracked online softmax (defer-max THR) in log2 domain, raw v_exp_f32.
// ---------------------------------------------------------------------------
__global__ __launch_bounds__(512, 4) void attn_kernel(
    const unsigned short* __restrict__ qhi, const unsigned short* __restrict__ qlo,
    const unsigned short* __restrict__ khi, const unsigned short* __restrict__ klo,
    const unsigned short* __restrict__ vt,
    float* __restrict__ accw, float* __restrict__ mlw)
{
    __shared__ __align__(16) unsigned short lds[2 * 2 * 6144]; // 48KB
    const int tid = threadIdx.x;
    const int tid8 = tid & 255;
    const int grp = tid >> 8;               // key-half group
    const int xcd = blockIdx.x & 7;
    const int qblk = blockIdx.x >> 3;       // 0..63
    const int b = xcd >> 2, ks = xcd & 3;
    const int lane = tid & 63, wv = (tid >> 6) & 3;
    const int l15 = lane & 15, g = lane >> 4;

    // q fragments (registers, whole kernel); q is pre-scaled by log2e/8
    bf16x8 qh[2], ql[2];
    {
        int qr = (b * 4096 + qblk * 64 + wv * 16 + l15) * 64;
        qh[0] = *(const bf16x8*)&qhi[qr + 8 * g];
        qh[1] = *(const bf16x8*)&qhi[qr + 32 + 8 * g];
        ql[0] = *(const bf16x8*)&qlo[qr + 8 * g];
        ql[1] = *(const bf16x8*)&qlo[qr + 32 + 8 * g];
    }

    unsigned short* GL = lds + grp * 12288;
    // K staging: XOR-swizzled b128 slots (proven conflict-free).
    const int trow = tid8 >> 3, tc = tid8 & 7;
    const int kdst = trow * 64 + 8 * (tc ^ (trow & 7));
    // V staging: thread (vd = row, vs) holds keys 8vs..8vs+7; store as two
    // b64 halves at group positions (2vs)^s and (2vs+1)^s, s = (vd>>1)&7.
    const int vd = tid8 >> 2, vs = tid8 & 3;
    const int vsw = (vd >> 1) & 7;
    const int vdst0 = 4096 + vd * 32 + 4 * ((2 * vs) ^ vsw);
    const int vdst1 = 4096 + vd * 32 + 4 * ((2 * vs + 1) ^ vsw);
    const int keybase = ks * 4096 + grp * 2048;
    const unsigned short* gkh = khi + (b * 16384 + keybase + trow) * 64 + 8 * tc;
    const unsigned short* gkl = klo + (b * 16384 + keybase + trow) * 64 + 8 * tc;
    const unsigned short* gv  = vt  + (b * 64 + vd) * 16384 + keybase + 8 * vs;

    { // prologue: stage tile 0 into buffer 0
        int4 a = *(const int4*)gkh;
        int4 c = *(const int4*)gkl;
        int4 v = *(const int4*)gv;
        *(int4*)&GL[kdst] = a;
        *(int4*)&GL[2048 + kdst] = c;
        *(int2*)&GL[vdst0] = make_int2(v.x, v.y);
        *(int2*)&GL[vdst1] = make_int2(v.z, v.w);
    }
    __syncthreads();

    // fragment LDS read offsets
    int koff[2][2], voff[4][2];
    #pragma unroll
    for (int rt = 0; rt < 2; ++rt) {
        int row = rt * 16 + l15;
        #pragma unroll
        for (int kc = 0; kc < 2; ++kc)
            koff[rt][kc] = row * 64 + 8 * ((4 * kc + g) ^ (row & 7));
    }
    {
        const int rs = (l15 >> 1) & 7;   // row-XOR for V ((r>>1)&7, dt-indep)
        #pragma unroll
        for (int dt = 0; dt < 4; ++dt) {
            int r = dt * 16 + l15;
            voff[dt][0] = 4096 + r * 32 + 4 * (g ^ rs);        // keys 4g..4g+3
            voff[dt][1] = 4096 + r * 32 + 4 * ((4 + g) ^ rs);  // keys 16+4g..+3
        }
    }

    float m = -INFINITY, lsum = 0.f;
    f32x4 acc[4];
    #pragma unroll
    for (int dt = 0; dt < 4; ++dt) acc[dt] = (f32x4){0.f, 0.f, 0.f, 0.f};

    const int NIT = 64;   // 2048 keys / 32
    int buf = 0;
    for (int it = 0; it < NIT; ++it) {
        int4 na, nc, nv;
        const bool pf = (it + 1 < NIT);
        if (pf) { // T14: issue next-tile loads early; latency hides under compute
            na = *(const int4*)(gkh + (it + 1) * 2048);
            nc = *(const int4*)(gkl + (it + 1) * 2048);
            nv = *(const int4*)(gv + (it + 1) * 32);
        }
        const unsigned short* L = GL + buf * 6144;

        // QK^T (swapped): c[rt] holds S'[key = 16rt+4g+r][q = l15], log2 units
        f32x4 c[2];
        __builtin_amdgcn_s_setprio(1);
        #pragma unroll
        for (int rt = 0; rt < 2; ++rt) {
            bf16x8 a0 = *(const bf16x8*)&L[koff[rt][0]];
            bf16x8 a1 = *(const bf16x8*)&L[koff[rt][1]];
            bf16x8 b0 = *(const bf16x8*)&L[2048 + koff[rt][0]];
            bf16x8 b1 = *(const bf16x8*)&L[2048 + koff[rt][1]];
            f32x4 cc = (f32x4){0.f, 0.f, 0.f, 0.f};
            cc = __builtin_amdgcn_mfma_f32_16x16x32_bf16(a0, qh[0], cc, 0, 0, 0);
            cc = __builtin_amdgcn_mfma_f32_16x16x32_bf16(a1, qh[1], cc, 0, 0, 0);
            cc = __builtin_amdgcn_mfma_f32_16x16x32_bf16(a0, ql[0], cc, 0, 0, 0);
            cc = __builtin_amdgcn_mfma_f32_16x16x32_bf16(a1, ql[1], cc, 0, 0, 0);
            cc = __builtin_amdgcn_mfma_f32_16x16x32_bf16(b0, qh[0], cc, 0, 0, 0);
            cc = __builtin_amdgcn_mfma_f32_16x16x32_bf16(b1, qh[1], cc, 0, 0, 0);
            c[rt] = cc;
        }
        __builtin_amdgcn_s_setprio(0);

        float s[8];
        #pragma unroll
        for (int r = 0; r < 4; ++r) { s[r] = c[0][r]; s[4 + r] = c[1][r]; }
        float pmax = fmaxf(fmaxf(fmaxf(s[0], s[1]), fmaxf(s[2], s[3])),
                           fmaxf(fmaxf(s[4], s[5]), fmaxf(s[6], s[7])));
        if (!__all(pmax <= m + 11.5f)) {     // T13 defer-max, THR = 8 nats (log2 units)
            float tmax = pmax;
            #pragma unroll
            for (int off = 1; off < 64; off <<= 1) tmax = fmaxf(tmax, __shfl_xor(tmax, off, 64));
            if (tmax > m) {
                float fac = exp2_raw(m - tmax);
                m = tmax; lsum *= fac;
                #pragma unroll
                for (int dt = 0; dt < 4; ++dt) {
                    acc[dt][0] *= fac; acc[dt][1] *= fac; acc[dt][2] *= fac; acc[dt][3] *= fac;
                }
            }
        }
        float p[8];
        float psum = 0.f;
        #pragma unroll
        for (int q = 0; q < 8; ++q) {
            p[q] = exp2_raw(s[q] - m);
            psum += p[q];
        }
        lsum += psum;
        union { unsigned int u[4]; bf16x8 v8; } pk;
        asm("v_cvt_pk_bf16_f32 %0, %1, %2" : "=v"(pk.u[0]) : "v"(p[0]), "v"(p[1]));
        asm("v_cvt_pk_bf16_f32 %0, %1, %2" : "=v"(pk.u[1]) : "v"(p[2]), "v"(p[3]));
        asm("v_cvt_pk_bf16_f32 %0, %1, %2" : "=v"(pk.u[2]) : "v"(p[4]), "v"(p[5]));
        asm("v_cvt_pk_bf16_f32 %0, %1, %2" : "=v"(pk.u[3]) : "v"(p[6]), "v"(p[7]));
        bf16x8 pa = pk.v8;

        __builtin_amdgcn_s_setprio(1);
        #pragma unroll
        for (int dt = 0; dt < 4; ++dt) {
            bf16x4 va = *(const bf16x4*)&L[voff[dt][0]];
            bf16x4 vb = *(const bf16x4*)&L[voff[dt][1]];
            bf16x8 vf = {va[0], va[1], va[2], va[3], vb[0], vb[1], vb[2], vb[3]};
            acc[dt] = __builtin_amdgcn_mfma_f32_16x16x32_bf16(pa, vf, acc[dt], 0, 0, 0);
        }
        __builtin_amdgcn_s_setprio(0);

        if (pf) { // write prefetched tile into other buffer
            unsigned short* D = GL + (buf ^ 1) * 6144;
            *(int4*)&D[kdst] = na;
            *(int4*)&D[2048 + kdst] = nc;
            *(int2*)&D[vdst0] = make_int2(nv.x, nv.y);
            *(int2*)&D[vdst1] = make_int2(nv.z, nv.w);
        }
        __syncthreads();
        buf ^= 1;
    }

    // per-wave reduce lsum (m already wave-uniform)
    #pragma unroll
    for (int off = 1; off < 64; off <<= 1) lsum += __shfl_xor(lsum, off, 64);

    // group merge via LDS: grp1 publishes, grp0 merges (lane-symmetric slots)
    float* mrg = (float*)lds;
    const int mbase = wv * 1026;
    if (grp == 1) {
        #pragma unroll
        for (int dt = 0; dt < 4; ++dt)
            #pragma unroll
            for (int r = 0; r < 4; ++r)
                mrg[mbase + (dt * 4 + r) * 64 + lane] = acc[dt][r];
        if (lane == 0) { mrg[mbase + 1024] = m; mrg[mbase + 1025] = lsum; }
    }
    __syncthreads();
    if (grp == 0) {
        float mB = mrg[mbase + 1024];
        float lB = mrg[mbase + 1025];
        float M = fmaxf(m, mB);
        float fA = exp2_raw(m - M), fB = exp2_raw(mB - M);
        float lOut = lsum * fA + lB * fB;
        const int unit = ((b * 64 + qblk) * 4 + ks) * 4 + wv;
        if (lane == 0) { mlw[2 * unit] = M; mlw[2 * unit + 1] = lOut; }
        float* ab = accw + unit * 1024;
        #pragma unroll
        for (int dt = 0; dt < 4; ++dt)
            #pragma unroll
            for (int r = 0; r < 4; ++r) {
                float v = acc[dt][r] * fA + mrg[mbase + (dt * 4 + r) * 64 + lane] * fB;
                ab[(4 * g + r) * 64 + dt * 16 + l15] = v;
            }
    }
}

// ---------------------------------------------------------------------------
// finalize: per batch M = max m_u, L = sum l_u 2^{m_u-M}; out = sum_ks acc*2^{m-M}/L
// grid 128 = (b, qblk). out layout [B][4096][64] == reference reshape (flat no-op).
// ---------------------------------------------------------------------------
__global__ __launch_bounds__(256) void finalize_kernel(
    const float* __restrict__ accw, const float* __restrict__ mlw, float* __restrict__ out)
{
    const int b = blockIdx.x >> 6;
    const int qblk = blockIdx.x & 63;
    const int tid = threadIdx.x;
    __shared__ float red[256];
    const float* mlb = mlw + b * 2048;

    float mloc = -INFINITY;
    for (int u = tid; u < 1024; u += 256) mloc = fmaxf(mloc, mlb[2 * u]);
    red[tid] = mloc; __syncthreads();
    for (int s = 128; s > 0; s >>= 1) {
        if (tid < s) red[tid] = fmaxf(red[tid], red[tid + s]);
        __syncthreads();
    }
    const float Mb = red[0];
    __syncthreads();
    float lloc = 0.f;
    for (int u = tid; u < 1024; u += 256) lloc += mlb[2 * u + 1] * exp2f(mlb[2 * u] - Mb);
    red[tid] = lloc; __syncthreads();
    for (int s = 128; s > 0; s >>= 1) {
        if (tid < s) red[tid] += red[tid + s];
        __syncthreads();
    }
    const float invL = 1.0f / red[0];

    const int d = tid & 63, wgrp = tid >> 6;
    float scl[4];
    int units[4];
    #pragma unroll
    for (int ks = 0; ks < 4; ++ks) {
        units[ks] = ((b * 64 + qblk) * 4 + ks) * 4 + wgrp;
        scl[ks] = exp2f(mlw[2 * units[ks]] - Mb) * invL;
    }
    #pragma unroll
    for (int rr = 0; rr < 16; ++rr) {
        float o = 0.f;
        #pragma unroll
        for (int ks = 0; ks < 4; ++ks)
            o = fmaf(accw[units[ks] * 1024 + rr * 64 + d], scl[ks], o);
        out[(b * 4096 + qblk * 64 + wgrp * 16 + rr) * 64 + d] = o;
    }
}

// ---------------------------------------------------------------------------
extern "C" void kernel_launch(void* const* d_in, const int* in_sizes, int n_in,
                              void* d_out, int out_size, void* d_ws, size_t ws_size,
                              hipStream_t stream) {
    const float* zx   = (const float*)d_in[0];
    const float* zy   = (const float*)d_in[1];
    const float* q_w  = (const float*)d_in[2];
    const float* q_b  = (const float*)d_in[3];
    const float* px_w = (const float*)d_in[4];
    const float* px_b = (const float*)d_in[5];
    const float* k_w  = (const float*)d_in[6];
    const float* k_b  = (const float*)d_in[7];
    const float* py_w = (const float*)d_in[8];
    const float* py_b = (const float*)d_in[9];
    const float* v_w  = (const float*)d_in[10];
    const float* v_b  = (const float*)d_in[11];

    unsigned short* qhi = (unsigned short*)d_ws;          // [2][4096][64]
    unsigned short* qlo = qhi + 524288;                   // [2][4096][64]
    unsigned short* khi = qlo + 524288;                   // [2][16384][64]
    unsigned short* klo = khi + 2097152;                  // [2][16384][64]
    unsigned short* vt  = klo + 2097152;                  // [2][64][16384] (transposed)
    float* accw = (float*)(vt + 2097152);                 // [2048 units][16][64]
    float* mlw  = accw + 2097152;                         // [2048 units][2]
    float* out  = (float*)d_out;

    proj_q_kernel<<<128, 256, 0, stream>>>(zx, q_w, q_b, px_w, px_b, qhi, qlo);
    proj_kv_kernel<<<512, 256, 0, stream>>>(zy, k_w, k_b, py_w, py_b, v_w, v_b, khi, klo, vt);
    attn_kernel<<<512, 512, 0, stream>>>(qhi, qlo, khi, klo, vt, accw, mlw);
    finalize_kernel<<<128, 256, 0, stream>>>(accw, mlw, out);
}